// Round 15
// baseline (414.570 us; speedup 1.0000x reference)
//
#include <hip/hip_runtime.h>
#include <hip/hip_bf16.h>

#define DEV __device__ __forceinline__

typedef __attribute__((ext_vector_type(8))) __bf16 bf16x8;
typedef __attribute__((ext_vector_type(8))) short s16x8;
typedef __attribute__((ext_vector_type(4))) float f32x4;
typedef __attribute__((ext_vector_type(2))) unsigned long long u64x2;

DEV f32x4 mfma16(s16x8 a, s16x8 b, f32x4 c){
  return __builtin_amdgcn_mfma_f32_16x16x32_bf16(
      __builtin_bit_cast(bf16x8, a), __builtin_bit_cast(bf16x8, b), c, 0, 0, 0);
}

// hardware cvt_pk path (compiler emits v_cvt_pk_bf16_f32)
DEV unsigned int cvtpk(float a, float b){
  float2 t; t.x = a; t.y = b;
  __hip_bfloat162 h = __float22bfloat162_rn(t);
  unsigned int r;
  __builtin_memcpy(&r, &h, 4);
  return r;
}

DEV unsigned short f2bf(float f){
  __hip_bfloat16 h = __float2bfloat16(f);
  unsigned short r;
  __builtin_memcpy(&r, &h, 2);
  return r;
}

DEV float bf2f(unsigned short u){
  return __builtin_bit_cast(float, ((unsigned int)u) << 16);
}

DEV unsigned long long pack4(float4 v){
  return (unsigned long long)cvtpk(v.x, v.y) | ((unsigned long long)cvtpk(v.z, v.w) << 32);
}

DEV unsigned long long pack4f(float a, float b, float c, float d){
  return (unsigned long long)cvtpk(a, b) | ((unsigned long long)cvtpk(c, d) << 32);
}

DEV void async16(const void* g, void* l){
  __builtin_amdgcn_global_load_lds(
      (const __attribute__((address_space(1))) unsigned int*)g,
      (__attribute__((address_space(3))) unsigned int*)l, 16, 0, 0);
}

// ---------------- convert inputs to bf16 ----------------
__global__ __launch_bounds__(256) void cvt_kernel(
    const float* __restrict__ x, const float* __restrict__ wq, const float* __restrict__ wk,
    const float* __restrict__ wv, const float* __restrict__ wo,
    const float* __restrict__ bq, const float* __restrict__ bk, const float* __restrict__ bv,
    unsigned long long* __restrict__ xb, unsigned long long* __restrict__ wqkvb,
    unsigned long long* __restrict__ wob, float4* __restrict__ bqkv)
{
  const int i = blockIdx.x * 256 + threadIdx.x;
  const int X4 = 1048576, W4 = 262144;
  if (i < X4){
    xb[i] = pack4(((const float4*)x)[i]);
  } else if (i < X4 + 3*W4){
    int j = i - X4;
    const float* src = (j < W4) ? wq : (j < 2*W4) ? wk : wv;
    int jj = (j < W4) ? j : (j < 2*W4) ? (j - W4) : (j - 2*W4);
    wqkvb[j] = pack4(((const float4*)src)[jj]);
  } else if (i < X4 + 4*W4){
    int j = i - X4 - 3*W4;
    wob[j] = pack4(((const float4*)wo)[j]);
  } else if (i < X4 + 4*W4 + 768){
    int j = i - X4 - 4*W4;
    const float* src = (j < 256) ? bq : (j < 512) ? bk : bv;
    int jj = (j < 256) ? j : (j < 512) ? (j - 256) : (j - 512);
    bqkv[j] = ((const float4*)src)[jj];
  }
}

// ---------------- 128x128 NT GEMM (QKV fused), K=1024, BK=64, swizzled LDS ----------------
__global__ __launch_bounds__(256) void gemm_qkv(
    const unsigned short* __restrict__ A,
    const unsigned short* __restrict__ B,
    const float* __restrict__ bias,
    unsigned short* __restrict__ oq,
    unsigned short* __restrict__ okk,
    unsigned short* __restrict__ ovt)
{
  __shared__ __align__(16) char smem[32768];
  char* As = smem;
  char* Bs = smem + 16384;
  const int tid = threadIdx.x;
  const int l = tid & 63, w = tid >> 6, g = l >> 4;

  const int orig = blockIdx.x;
  const int lin = (orig & 7) * 96 + (orig >> 3);
  const int m0 = (lin / 24) * 128, n0 = (lin % 24) * 128;
  const int rowbytes = 2048;

  f32x4 acc[4][4] = {};
  const int wr = w >> 1, wc = w & 1;
  const int wm = wr * 64, wn = wc * 64;

  const int srow = w * 32 + (l >> 3);
  const int scol = (((l & 7) ^ (l >> 3)) << 4);
  const char* Abp = (const char*)A + (size_t)(m0 + srow) * rowbytes + scol;
  const char* Bbp = (const char*)B + (size_t)(n0 + srow) * rowbytes + scol;
  char* Asw = As + w * 4096;
  char* Bsw = Bs + w * 4096;

  int aoff[4][2], boff[4][2];
  for (int mf = 0; mf < 4; ++mf)
    for (int ks = 0; ks < 2; ++ks){
      int ra = wm + mf * 16 + (l & 15);
      aoff[mf][ks] = ra * 128 + ((ks * 64 + g * 16) ^ ((l & 7) << 4));
      int rb = wn + mf * 16 + (l & 15);
      boff[mf][ks] = rb * 128 + ((ks * 64 + g * 16) ^ ((l & 7) << 4));
    }

  for (int kt = 0; kt < 16; ++kt){
    const char* ab = Abp + kt * 128;
    const char* bb = Bbp + kt * 128;
    for (int i = 0; i < 4; ++i){
      async16(ab + (size_t)i * 8 * rowbytes, Asw + i * 1024);
      async16(bb + (size_t)i * 8 * rowbytes, Bsw + i * 1024);
    }
    __syncthreads();
    for (int ks = 0; ks < 2; ++ks){
      s16x8 af[4], bf[4];
      for (int mf = 0; mf < 4; ++mf) af[mf] = *(const s16x8*)(As + aoff[mf][ks]);
      for (int nf = 0; nf < 4; ++nf) bf[nf] = *(const s16x8*)(Bs + boff[nf][ks]);
      for (int mf = 0; mf < 4; ++mf)
        for (int nf = 0; nf < 4; ++nf)
          acc[mf][nf] = mfma16(af[mf], bf[nf], acc[mf][nf]);
    }
    __syncthreads();
  }

  if (n0 >= 2048){
    for (int nf = 0; nf < 4; ++nf){
      int nloc = wn + nf * 16 + (l & 15);
      float bs = bias[n0 + nloc];
      for (int mf = 0; mf < 4; ++mf){
        int mby = (wm + mf * 16 + g * 4) * 2;
        unsigned long long pk = pack4f(acc[mf][nf][0] + bs, acc[mf][nf][1] + bs,
                                       acc[mf][nf][2] + bs, acc[mf][nf][3] + bs);
        *(unsigned long long*)(smem + nloc * 256 + (mby ^ ((nloc & 15) << 4))) = pk;
      }
    }
    __syncthreads();
    int b2 = m0 >> 11, s0 = m0 & 2047;
    for (int i = 0; i < 8; ++i){
      int idx = i * 256 + tid;
      int row = idx >> 4, c8 = (idx & 15) * 8;
      s16x8 vv = *(const s16x8*)(smem + row * 256 + ((c8 * 2) ^ ((row & 15) << 4)));
      *(s16x8*)(ovt + (size_t)(b2 * 1024 + (n0 - 2048) + row) * 2048 + s0 + c8) = vv;
    }
    return;
  }

  for (int mf = 0; mf < 4; ++mf)
    for (int nf = 0; nf < 4; ++nf)
      for (int r = 0; r < 4; ++r){
        int grow = m0 + wm + mf * 16 + g * 4 + r;
        int n = n0 + wn + nf * 16 + (l & 15);
        float v = acc[mf][nf][r] + bias[n];
        if (n < 1024) oq [(size_t)grow * 1024 + n]          = f2bf(v);
        else          okk[(size_t)grow * 1024 + (n - 1024)] = f2bf(v);
      }
}

// ---------------- out-proj GEMM: 128x64 tiles, 512 blocks (2/CU), coalesced f32 epilogue ----
__global__ __launch_bounds__(256) void gemm_out(
    const unsigned short* __restrict__ A,
    const unsigned short* __restrict__ B,
    const float* __restrict__ bias,
    float* __restrict__ of)
{
  __shared__ __align__(16) char smem[32768];
  char* As = smem;
  char* Bs = smem + 16384;
  const int tid = threadIdx.x, l = tid & 63, w = tid >> 6, g = l >> 4;
  const int orig = blockIdx.x;
  const int lin = (orig & 7) * 64 + (orig >> 3);
  const int m0 = (lin >> 4) * 128, n0 = (lin & 15) * 64;
  const int rowbytes = 2048;

  f32x4 acc[2][4] = {};
  const int wm = w * 32;

  const int scol = (((l & 7) ^ (l >> 3)) << 4);
  const char* Abp = (const char*)A + (size_t)(m0 + w * 32 + (l >> 3)) * rowbytes + scol;
  const char* Bbp = (const char*)B + (size_t)(n0 + w * 16 + (l >> 3)) * rowbytes + scol;
  char* Asw = As + w * 4096;
  char* Bsw = Bs + w * 2048;

  int aoff[2][2], boff[4][2];
  for (int ks = 0; ks < 2; ++ks){
    for (int mf = 0; mf < 2; ++mf){
      int ra = wm + mf * 16 + (l & 15);
      aoff[mf][ks] = ra * 128 + ((ks * 64 + g * 16) ^ ((l & 7) << 4));
    }
    for (int nf = 0; nf < 4; ++nf){
      int rb = nf * 16 + (l & 15);
      boff[nf][ks] = rb * 128 + ((ks * 64 + g * 16) ^ ((l & 7) << 4));
    }
  }

  for (int kt = 0; kt < 16; ++kt){
    for (int i = 0; i < 4; ++i)
      async16(Abp + kt * 128 + (size_t)i * 8 * rowbytes, Asw + i * 1024);
    for (int i = 0; i < 2; ++i)
      async16(Bbp + kt * 128 + (size_t)i * 8 * rowbytes, Bsw + i * 1024);
    __syncthreads();
    for (int ks = 0; ks < 2; ++ks){
      s16x8 af[2], bf[4];
      for (int mf = 0; mf < 2; ++mf) af[mf] = *(const s16x8*)(As + aoff[mf][ks]);
      for (int nf = 0; nf < 4; ++nf) bf[nf] = *(const s16x8*)(Bs + boff[nf][ks]);
      for (int mf = 0; mf < 2; ++mf)
        for (int nf = 0; nf < 4; ++nf)
          acc[mf][nf] = mfma16(af[mf], bf[nf], acc[mf][nf]);
    }
    __syncthreads();
  }

  __syncthreads();
  char* stg = smem + w * 8192;
  float bv4[4];
  for (int nf = 0; nf < 4; ++nf) bv4[nf] = bias[n0 + nf * 16 + (l & 15)];
  for (int mf = 0; mf < 2; ++mf)
    for (int nf = 0; nf < 4; ++nf)
      for (int r = 0; r < 4; ++r){
        int row = mf * 16 + g * 4 + r;
        int colb = (nf * 16 + (l & 15)) * 4;
        *(float*)(stg + row * 256 + (colb ^ ((row & 7) << 4))) = acc[mf][nf][r] + bv4[nf];
      }
  __syncthreads();
  for (int t = 0; t < 8; ++t){
    int row = t * 4 + (l >> 4);
    int colb = ((l & 15) * 16) ^ ((row & 7) << 4);
    f32x4 v = *(const f32x4*)(stg + row * 256 + colb);
    __builtin_nontemporal_store(v, (f32x4*)&of[(size_t)(m0 + wm + row) * 1024 + n0 + (l & 15) * 4]);
  }
}

// ---------------- attention: SINGLE-PASS, QBLK=32, 8 waves x 256-key stripes (R11 champion). ----
__global__ __launch_bounds__(512) void attn_kernel(
    const unsigned short* __restrict__ qb,
    const unsigned short* __restrict__ kb,
    const unsigned short* __restrict__ vtb,
    const int* __restrict__ mask,
    float* __restrict__ Pout,
    unsigned short* __restrict__ attnb)
{
  const int flat = blockIdx.x;
  const int sw = (flat & 7) * 256 + (flat >> 3);
  const int qt = sw & 63, h = (sw >> 6) & 15, b = sw >> 10;
  const int tid = threadIdx.x, l = tid & 63, w = tid >> 6, g = l >> 4;
  const int q0 = qt * 32;

  __shared__ __align__(16) unsigned long long estu[16384]; // 128 KB: [32 q][4096 B] E; reused as 8 pv bufs
  __shared__ float maskadd[2048];                          // 8 KB
  __shared__ float zpart[8][32];
  __shared__ float zfullinv[32];

  char* Ebase = (char*)estu;

  for (int i = tid; i < 2048; i += 512)
    maskadd[i] = mask[b * 2048 + i] ? 0.0f : -1e30f;

  s16x8 qf[2][2];
  for (int mf = 0; mf < 2; ++mf)
    for (int ks = 0; ks < 2; ++ks)
      qf[mf][ks] = *(const s16x8*)(qb + (size_t)(b*2048 + q0 + mf*16 + (l&15)) * 1024
                                   + h*64 + ks*32 + g*8);

  const unsigned short* Kb = kb + (size_t)b * 2048 * 1024 + h * 64;
  const unsigned short* Vb = vtb + ((size_t)b * 1024 + h * 64) * 2048;

  __syncthreads();

  // ---- pass 1: QK^T + exp + E->LDS + Z (wave w owns keys [w*256, w*256+256)) ----
  float zacc[2] = {0.0f, 0.0f};
  for (int jj = 0; jj < 4; ++jj){
    const int kk0 = w * 256 + jj * 64;
    const int cb = kk0 * 2;
    f32x4 c[2][4] = {};
    for (int nh = 0; nh < 2; ++nh){
      s16x8 kf[2][2];
      for (int n2 = 0; n2 < 2; ++n2)
        for (int ks = 0; ks < 2; ++ks)
          kf[n2][ks] = *(const s16x8*)(Kb + (size_t)(kk0 + (nh*2+n2)*16 + (l&15)) * 1024 + ks*32 + g*8);
      __builtin_amdgcn_s_setprio(1);
      for (int ks = 0; ks < 2; ++ks)
        for (int mf = 0; mf < 2; ++mf)
          for (int n2 = 0; n2 < 2; ++n2)
            c[mf][nh*2+n2] = mfma16(kf[n2][ks], qf[mf][ks], c[mf][nh*2+n2]);
      __builtin_amdgcn_s_setprio(0);
    }
    for (int mf = 0; mf < 2; ++mf){
      int q = mf*16 + (l & 15);
      for (int nf = 0; nf < 4; ++nf){
        f32x4 ma = *(const f32x4*)&maskadd[kk0 + nf*16 + g*4];
        f32x4 e;
        for (int r = 0; r < 4; ++r){
          e[r] = __expf(fmaf(c[mf][nf][r], 0.125f, ma[r]));
          zacc[mf] += e[r];
        }
        *(unsigned long long*)(Ebase + q*4096 + cb + ((nf*32 + g*8) ^ ((q & 7) << 4))) =
            pack4f(e[0], e[1], e[2], e[3]);
      }
    }
  }
  for (int mf = 0; mf < 2; ++mf){
    float z = zacc[mf];
    z += __shfl_xor(z, 16, 64);
    z += __shfl_xor(z, 32, 64);
    zacc[mf] = z;
  }
  if (g == 0){
    zpart[w][l & 15]        = zacc[0];
    zpart[w][16 + (l & 15)] = zacc[1];
  }
  __syncthreads();
  if (tid < 32){
    float s = 0.0f;
    for (int ww = 0; ww < 8; ++ww) s += zpart[ww][tid];
    zfullinv[tid] = 1.0f / s;
  }
  __syncthreads();

  // ---- pass 2 (E read-only): PV partials + coalesced nt P store ----
  float* Pb = Pout + ((size_t)(b*16 + h) * 2048 + q0) * 2048;
  f32x4 pv[2][4] = {};
  for (int jj = 0; jj < 4; ++jj){
    const int kk0 = w * 256 + jj * 64;
    const int cb = kk0 * 2;
    s16x8 pa[2][2];
    for (int mf = 0; mf < 2; ++mf)
      for (int ks = 0; ks < 2; ++ks){
        int q = mf*16 + (l & 15);
        const unsigned long long* pp =
            (const unsigned long long*)(Ebase + q*4096 + cb + ((ks*64 + g*16) ^ ((q & 7) << 4)));
        u64x2 t; t[0] = pp[0]; t[1] = pp[1];
        pa[mf][ks] = __builtin_bit_cast(s16x8, t);
      }
    for (int dh = 0; dh < 2; ++dh){
      s16x8 vf[2][2];
      for (int d2 = 0; d2 < 2; ++d2)
        for (int ks = 0; ks < 2; ++ks)
          vf[d2][ks] = *(const s16x8*)(Vb + (size_t)((dh*2+d2)*16 + (l&15)) * 2048 + kk0 + ks*32 + g*8);
      __builtin_amdgcn_s_setprio(1);
      for (int ks = 0; ks < 2; ++ks)
        for (int mf = 0; mf < 2; ++mf)
          for (int d2 = 0; d2 < 2; ++d2)
            pv[mf][dh*2+d2] = mfma16(pa[mf][ks], vf[d2][ks], pv[mf][dh*2+d2]);
      __builtin_amdgcn_s_setprio(0);
    }
    for (int t = 0; t < 8; ++t){
      int row = t * 4 + (l >> 4);
      unsigned long long pk =
          *(const unsigned long long*)(Ebase + row*4096 + cb + (((l & 15) * 8) ^ ((row & 7) << 4)));
      float zr = zfullinv[row];
      f32x4 ps;
      ps[0] = bf2f((unsigned short)(pk      )) * zr;
      ps[1] = bf2f((unsigned short)(pk >> 16)) * zr;
      ps[2] = bf2f((unsigned short)(pk >> 32)) * zr;
      ps[3] = bf2f((unsigned short)(pk >> 48)) * zr;
      __builtin_nontemporal_store(ps, (f32x4*)&Pb[(size_t)row * 2048 + kk0 + (l & 15) * 4]);
    }
  }

  // ---- combine: 8 partial bufs overlay dead E (barrier-fenced), tree sum, scale, write attnb ----
  __syncthreads();
  char* bufw = Ebase + w * 8192;
  for (int mf = 0; mf < 2; ++mf)
    for (int dn = 0; dn < 4; ++dn)
      for (int r = 0; r < 4; ++r){
        int row = mf*16 + g*4 + r, col = dn*16 + (l & 15);
        *(float*)(bufw + row*256 + ((col*4) ^ (((row >> 2) & 3) << 6))) = pv[mf][dn][r];
      }
  __syncthreads();
  {
    int row = tid >> 4, c4 = (tid & 15) * 4;
    int off = row*256 + ((c4*4) ^ (((row >> 2) & 3) << 6));
    f32x4 s = {};
    for (int ww = 0; ww < 8; ++ww)
      s += *(const f32x4*)(Ebase + ww*8192 + off);
    float zr = zfullinv[row];
    unsigned long long ov = pack4f(s[0]*zr, s[1]*zr, s[2]*zr, s[3]*zr);
    *(unsigned long long*)&attnb[(size_t)(b*2048 + q0 + row) * 1024 + h*64 + c4] = ov;
  }
}

extern "C" void kernel_launch(void* const* d_in, const int* in_sizes, int n_in,
                              void* d_out, int out_size, void* d_ws, size_t ws_size,
                              hipStream_t stream)
{
  const float* x  = (const float*)d_in[0];
  const int* mask = (const int*)d_in[1];
  const float* wq = (const float*)d_in[2];
  const float* bq = (const float*)d_in[3];
  const float* wk = (const float*)d_in[4];
  const float* bk = (const float*)d_in[5];
  const float* wv = (const float*)d_in[6];
  const float* bv = (const float*)d_in[7];
  const float* wo = (const float*)d_in[8];
  const float* bo = (const float*)d_in[9];

  char* ws = (char*)d_ws;
  unsigned short* xb    = (unsigned short*)(ws);                 // 8 MB
  unsigned short* wqkvb = (unsigned short*)(ws + 8388608);       // 6 MB
  unsigned short* wob   = (unsigned short*)(ws + 14680064);      // 2 MB
  float*          bqkv  = (float*)(ws + 16777216);               // 12 KB
  unsigned short* qb    = (unsigned short*)(ws + 16793600);      // 8 MB
  unsigned short* kb    = (unsigned short*)(ws + 25182208);      // 8 MB
  unsigned short* vtb   = (unsigned short*)(ws + 33570816);      // 8 MB  [b][d'][s]
  unsigned short* attnb = (unsigned short*)(ws + 41959424);      // 8 MB

  float* fout = (float*)d_out;
  float* Pout = fout + 4194304;

  cvt_kernel<<<8195, 256, 0, stream>>>(x, wq, wk, wv, wo, bq, bk, bv,
                                       (unsigned long long*)xb, (unsigned long long*)wqkvb,
                                       (unsigned long long*)wob, (float4*)bqkv);
  gemm_qkv<<<768, 256, 0, stream>>>(xb, wqkvb, bqkv, qb, kb, vtb);
  // MEASUREMENT: attn launched twice (idempotent — second launch writes identical bytes).
  // total - 244.6 = attn duration; resolves the per-kernel split the profiler can't show.
  attn_kernel<<<2048, 512, 0, stream>>>(qb, kb, vtb, mask, Pout, attnb);
  attn_kernel<<<2048, 512, 0, stream>>>(qb, kb, vtb, mask, Pout, attnb);
  gemm_out<<<512, 256, 0, stream>>>(attnb, wob, bo, fout);
}

// Round 16
// 304.574 us; speedup vs baseline: 1.3611x; 1.3611x over previous
//
#include <hip/hip_runtime.h>
#include <hip/hip_bf16.h>

#define DEV __device__ __forceinline__

typedef __attribute__((ext_vector_type(8))) __bf16 bf16x8;
typedef __attribute__((ext_vector_type(8))) short s16x8;
typedef __attribute__((ext_vector_type(4))) float f32x4;
typedef __attribute__((ext_vector_type(2))) unsigned long long u64x2;

DEV f32x4 mfma16(s16x8 a, s16x8 b, f32x4 c){
  return __builtin_amdgcn_mfma_f32_16x16x32_bf16(
      __builtin_bit_cast(bf16x8, a), __builtin_bit_cast(bf16x8, b), c, 0, 0, 0);
}

// hardware cvt_pk path (compiler emits v_cvt_pk_bf16_f32)
DEV unsigned int cvtpk(float a, float b){
  float2 t; t.x = a; t.y = b;
  __hip_bfloat162 h = __float22bfloat162_rn(t);
  unsigned int r;
  __builtin_memcpy(&r, &h, 4);
  return r;
}

DEV unsigned short f2bf(float f){
  __hip_bfloat16 h = __float2bfloat16(f);
  unsigned short r;
  __builtin_memcpy(&r, &h, 2);
  return r;
}

DEV float bf2f(unsigned short u){
  return __builtin_bit_cast(float, ((unsigned int)u) << 16);
}

DEV unsigned long long pack4(float4 v){
  return (unsigned long long)cvtpk(v.x, v.y) | ((unsigned long long)cvtpk(v.z, v.w) << 32);
}

DEV unsigned long long pack4f(float a, float b, float c, float d){
  return (unsigned long long)cvtpk(a, b) | ((unsigned long long)cvtpk(c, d) << 32);
}

DEV void async16(const void* g, void* l){
  __builtin_amdgcn_global_load_lds(
      (const __attribute__((address_space(1))) unsigned int*)g,
      (__attribute__((address_space(3))) unsigned int*)l, 16, 0, 0);
}

// ---------------- convert inputs to bf16 ----------------
__global__ __launch_bounds__(256) void cvt_kernel(
    const float* __restrict__ x, const float* __restrict__ wq, const float* __restrict__ wk,
    const float* __restrict__ wv, const float* __restrict__ wo,
    const float* __restrict__ bq, const float* __restrict__ bk, const float* __restrict__ bv,
    unsigned long long* __restrict__ xb, unsigned long long* __restrict__ wqkvb,
    unsigned long long* __restrict__ wob, float4* __restrict__ bqkv)
{
  const int i = blockIdx.x * 256 + threadIdx.x;
  const int X4 = 1048576, W4 = 262144;
  if (i < X4){
    xb[i] = pack4(((const float4*)x)[i]);
  } else if (i < X4 + 3*W4){
    int j = i - X4;
    const float* src = (j < W4) ? wq : (j < 2*W4) ? wk : wv;
    int jj = (j < W4) ? j : (j < 2*W4) ? (j - W4) : (j - 2*W4);
    wqkvb[j] = pack4(((const float4*)src)[jj]);
  } else if (i < X4 + 4*W4){
    int j = i - X4 - 3*W4;
    wob[j] = pack4(((const float4*)wo)[j]);
  } else if (i < X4 + 4*W4 + 768){
    int j = i - X4 - 4*W4;
    const float* src = (j < 256) ? bq : (j < 512) ? bk : bv;
    int jj = (j < 256) ? j : (j < 512) ? (j - 256) : (j - 512);
    bqkv[j] = ((const float4*)src)[jj];
  }
}

// ---------------- 128x128 NT GEMM (QKV fused), K=1024, BK=64, swizzled LDS ----------------
__global__ __launch_bounds__(256) void gemm_qkv(
    const unsigned short* __restrict__ A,
    const unsigned short* __restrict__ B,
    const float* __restrict__ bias,
    unsigned short* __restrict__ oq,
    unsigned short* __restrict__ okk,
    unsigned short* __restrict__ ovt)
{
  __shared__ __align__(16) char smem[32768];
  char* As = smem;
  char* Bs = smem + 16384;
  const int tid = threadIdx.x;
  const int l = tid & 63, w = tid >> 6, g = l >> 4;

  const int orig = blockIdx.x;
  const int lin = (orig & 7) * 96 + (orig >> 3);
  const int m0 = (lin / 24) * 128, n0 = (lin % 24) * 128;
  const int rowbytes = 2048;

  f32x4 acc[4][4] = {};
  const int wr = w >> 1, wc = w & 1;
  const int wm = wr * 64, wn = wc * 64;

  const int srow = w * 32 + (l >> 3);
  const int scol = (((l & 7) ^ (l >> 3)) << 4);
  const char* Abp = (const char*)A + (size_t)(m0 + srow) * rowbytes + scol;
  const char* Bbp = (const char*)B + (size_t)(n0 + srow) * rowbytes + scol;
  char* Asw = As + w * 4096;
  char* Bsw = Bs + w * 4096;

  int aoff[4][2], boff[4][2];
  for (int mf = 0; mf < 4; ++mf)
    for (int ks = 0; ks < 2; ++ks){
      int ra = wm + mf * 16 + (l & 15);
      aoff[mf][ks] = ra * 128 + ((ks * 64 + g * 16) ^ ((l & 7) << 4));
      int rb = wn + mf * 16 + (l & 15);
      boff[mf][ks] = rb * 128 + ((ks * 64 + g * 16) ^ ((l & 7) << 4));
    }

  for (int kt = 0; kt < 16; ++kt){
    const char* ab = Abp + kt * 128;
    const char* bb = Bbp + kt * 128;
    for (int i = 0; i < 4; ++i){
      async16(ab + (size_t)i * 8 * rowbytes, Asw + i * 1024);
      async16(bb + (size_t)i * 8 * rowbytes, Bsw + i * 1024);
    }
    __syncthreads();
    for (int ks = 0; ks < 2; ++ks){
      s16x8 af[4], bf[4];
      for (int mf = 0; mf < 4; ++mf) af[mf] = *(const s16x8*)(As + aoff[mf][ks]);
      for (int nf = 0; nf < 4; ++nf) bf[nf] = *(const s16x8*)(Bs + boff[nf][ks]);
      for (int mf = 0; mf < 4; ++mf)
        for (int nf = 0; nf < 4; ++nf)
          acc[mf][nf] = mfma16(af[mf], bf[nf], acc[mf][nf]);
    }
    __syncthreads();
  }

  if (n0 >= 2048){
    for (int nf = 0; nf < 4; ++nf){
      int nloc = wn + nf * 16 + (l & 15);
      float bs = bias[n0 + nloc];
      for (int mf = 0; mf < 4; ++mf){
        int mby = (wm + mf * 16 + g * 4) * 2;
        unsigned long long pk = pack4f(acc[mf][nf][0] + bs, acc[mf][nf][1] + bs,
                                       acc[mf][nf][2] + bs, acc[mf][nf][3] + bs);
        *(unsigned long long*)(smem + nloc * 256 + (mby ^ ((nloc & 15) << 4))) = pk;
      }
    }
    __syncthreads();
    int b2 = m0 >> 11, s0 = m0 & 2047;
    for (int i = 0; i < 8; ++i){
      int idx = i * 256 + tid;
      int row = idx >> 4, c8 = (idx & 15) * 8;
      s16x8 vv = *(const s16x8*)(smem + row * 256 + ((c8 * 2) ^ ((row & 15) << 4)));
      *(s16x8*)(ovt + (size_t)(b2 * 1024 + (n0 - 2048) + row) * 2048 + s0 + c8) = vv;
    }
    return;
  }

  for (int mf = 0; mf < 4; ++mf)
    for (int nf = 0; nf < 4; ++nf)
      for (int r = 0; r < 4; ++r){
        int grow = m0 + wm + mf * 16 + g * 4 + r;
        int n = n0 + wn + nf * 16 + (l & 15);
        float v = acc[mf][nf][r] + bias[n];
        if (n < 1024) oq [(size_t)grow * 1024 + n]          = f2bf(v);
        else          okk[(size_t)grow * 1024 + (n - 1024)] = f2bf(v);
      }
}

// ---------------- out-proj GEMM: 128x64 tiles, 512 blocks (2/CU), coalesced f32 epilogue ----
__global__ __launch_bounds__(256) void gemm_out(
    const unsigned short* __restrict__ A,
    const unsigned short* __restrict__ B,
    const float* __restrict__ bias,
    float* __restrict__ of)
{
  __shared__ __align__(16) char smem[32768];
  char* As = smem;
  char* Bs = smem + 16384;
  const int tid = threadIdx.x, l = tid & 63, w = tid >> 6, g = l >> 4;
  const int orig = blockIdx.x;
  const int lin = (orig & 7) * 64 + (orig >> 3);
  const int m0 = (lin >> 4) * 128, n0 = (lin & 15) * 64;
  const int rowbytes = 2048;

  f32x4 acc[2][4] = {};
  const int wm = w * 32;

  const int scol = (((l & 7) ^ (l >> 3)) << 4);
  const char* Abp = (const char*)A + (size_t)(m0 + w * 32 + (l >> 3)) * rowbytes + scol;
  const char* Bbp = (const char*)B + (size_t)(n0 + w * 16 + (l >> 3)) * rowbytes + scol;
  char* Asw = As + w * 4096;
  char* Bsw = Bs + w * 2048;

  int aoff[2][2], boff[4][2];
  for (int ks = 0; ks < 2; ++ks){
    for (int mf = 0; mf < 2; ++mf){
      int ra = wm + mf * 16 + (l & 15);
      aoff[mf][ks] = ra * 128 + ((ks * 64 + g * 16) ^ ((l & 7) << 4));
    }
    for (int nf = 0; nf < 4; ++nf){
      int rb = nf * 16 + (l & 15);
      boff[nf][ks] = rb * 128 + ((ks * 64 + g * 16) ^ ((l & 7) << 4));
    }
  }

  for (int kt = 0; kt < 16; ++kt){
    for (int i = 0; i < 4; ++i)
      async16(Abp + kt * 128 + (size_t)i * 8 * rowbytes, Asw + i * 1024);
    for (int i = 0; i < 2; ++i)
      async16(Bbp + kt * 128 + (size_t)i * 8 * rowbytes, Bsw + i * 1024);
    __syncthreads();
    for (int ks = 0; ks < 2; ++ks){
      s16x8 af[2], bf[4];
      for (int mf = 0; mf < 2; ++mf) af[mf] = *(const s16x8*)(As + aoff[mf][ks]);
      for (int nf = 0; nf < 4; ++nf) bf[nf] = *(const s16x8*)(Bs + boff[nf][ks]);
      for (int mf = 0; mf < 2; ++mf)
        for (int nf = 0; nf < 4; ++nf)
          acc[mf][nf] = mfma16(af[mf], bf[nf], acc[mf][nf]);
    }
    __syncthreads();
  }

  __syncthreads();
  char* stg = smem + w * 8192;
  float bv4[4];
  for (int nf = 0; nf < 4; ++nf) bv4[nf] = bias[n0 + nf * 16 + (l & 15)];
  for (int mf = 0; mf < 2; ++mf)
    for (int nf = 0; nf < 4; ++nf)
      for (int r = 0; r < 4; ++r){
        int row = mf * 16 + g * 4 + r;
        int colb = (nf * 16 + (l & 15)) * 4;
        *(float*)(stg + row * 256 + (colb ^ ((row & 7) << 4))) = acc[mf][nf][r] + bv4[nf];
      }
  __syncthreads();
  for (int t = 0; t < 8; ++t){
    int row = t * 4 + (l >> 4);
    int colb = ((l & 15) * 16) ^ ((row & 7) << 4);
    f32x4 v = *(const f32x4*)(stg + row * 256 + colb);
    __builtin_nontemporal_store(v, (f32x4*)&of[(size_t)(m0 + wm + row) * 1024 + n0 + (l & 15) * 4]);
  }
}

// ---------------- attention: SINGLE-PASS QBLK=32 (R11 base), restructured tail:
// pass1: 8 waves x 256-key stripes: QK^T + exp once -> E (bf16, swizzled) in 128 KB LDS + Z.
// Z-reduce barrier. pass2: wave (qi,di) computes FULL output tile [16q][16d] over all keys
// (no cross-wave combine, no combine barrier), writes attnb directly, then P-stores LAST
// with NO trailing barrier -> stores drain past s_endpgm, overlapping next block's pass1.
__global__ __launch_bounds__(512) void attn_kernel(
    const unsigned short* __restrict__ qb,
    const unsigned short* __restrict__ kb,
    const unsigned short* __restrict__ vtb,
    const int* __restrict__ mask,
    float* __restrict__ Pout,
    unsigned short* __restrict__ attnb)
{
  const int flat = blockIdx.x;
  const int sw = (flat & 7) * 256 + (flat >> 3);
  const int qt = sw & 63, h = (sw >> 6) & 15, b = sw >> 10;
  const int tid = threadIdx.x, l = tid & 63, w = tid >> 6, g = l >> 4;
  const int q0 = qt * 32;

  __shared__ __align__(16) unsigned long long estu[16384]; // 128 KB: [32 q][4096 B] E
  __shared__ float maskadd[2048];                          // 8 KB
  __shared__ float zpart[8][32];
  __shared__ float zfullinv[32];

  char* Ebase = (char*)estu;

  for (int i = tid; i < 2048; i += 512)
    maskadd[i] = mask[b * 2048 + i] ? 0.0f : -1e30f;

  s16x8 qf[2][2];
  for (int mf = 0; mf < 2; ++mf)
    for (int ks = 0; ks < 2; ++ks)
      qf[mf][ks] = *(const s16x8*)(qb + (size_t)(b*2048 + q0 + mf*16 + (l&15)) * 1024
                                   + h*64 + ks*32 + g*8);

  const unsigned short* Kb = kb + (size_t)b * 2048 * 1024 + h * 64;
  const unsigned short* Vb = vtb + ((size_t)b * 1024 + h * 64) * 2048;

  __syncthreads();

  // ---- pass 1: QK^T + exp + E->LDS + Z (wave w owns keys [w*256, w*256+256)) ----
  float zacc[2] = {0.0f, 0.0f};
  for (int jj = 0; jj < 4; ++jj){
    const int kk0 = w * 256 + jj * 64;
    const int cb = kk0 * 2;
    f32x4 c[2][4] = {};
    for (int nh = 0; nh < 2; ++nh){
      s16x8 kf[2][2];
      for (int n2 = 0; n2 < 2; ++n2)
        for (int ks = 0; ks < 2; ++ks)
          kf[n2][ks] = *(const s16x8*)(Kb + (size_t)(kk0 + (nh*2+n2)*16 + (l&15)) * 1024 + ks*32 + g*8);
      __builtin_amdgcn_s_setprio(1);
      for (int ks = 0; ks < 2; ++ks)
        for (int mf = 0; mf < 2; ++mf)
          for (int n2 = 0; n2 < 2; ++n2)
            c[mf][nh*2+n2] = mfma16(kf[n2][ks], qf[mf][ks], c[mf][nh*2+n2]);
      __builtin_amdgcn_s_setprio(0);
    }
    for (int mf = 0; mf < 2; ++mf){
      int q = mf*16 + (l & 15);
      for (int nf = 0; nf < 4; ++nf){
        f32x4 ma = *(const f32x4*)&maskadd[kk0 + nf*16 + g*4];
        f32x4 e;
        for (int r = 0; r < 4; ++r){
          e[r] = __expf(fmaf(c[mf][nf][r], 0.125f, ma[r]));
          zacc[mf] += e[r];
        }
        *(unsigned long long*)(Ebase + q*4096 + cb + ((nf*32 + g*8) ^ ((q & 7) << 4))) =
            pack4f(e[0], e[1], e[2], e[3]);
      }
    }
  }
  for (int mf = 0; mf < 2; ++mf){
    float z = zacc[mf];
    z += __shfl_xor(z, 16, 64);
    z += __shfl_xor(z, 32, 64);
    zacc[mf] = z;
  }
  if (g == 0){
    zpart[w][l & 15]        = zacc[0];
    zpart[w][16 + (l & 15)] = zacc[1];
  }
  __syncthreads();
  if (tid < 32){
    float s = 0.0f;
    for (int ww = 0; ww < 8; ++ww) s += zpart[ww][tid];
    zfullinv[tid] = 1.0f / s;
  }
  __syncthreads();   // E + zfullinv now visible block-wide

  // ---- pass 2a: PV — wave (qi,di) computes full [16q][16d] tile over ALL 2048 keys ----
  const int qi = w >> 2, di = w & 3;
  const int ql = qi*16 + (l & 15);                // E row (A-operand)
  const int qswz = ((ql & 7) << 4);
  const unsigned short* Vrow = Vb + (size_t)(di*16 + (l&15)) * 2048;
  f32x4 a4[4] = {};
  for (int c4 = 0; c4 < 16; ++c4){
#pragma unroll
    for (int u = 0; u < 4; ++u){
      const int c32 = c4*4 + u;
      const unsigned long long* pp = (const unsigned long long*)
          (Ebase + ql*4096 + (c32 >> 1)*128 + (((c32 & 1)*64 + g*16) ^ qswz));
      u64x2 t2; t2[0] = pp[0]; t2[1] = pp[1];
      s16x8 pa = __builtin_bit_cast(s16x8, t2);
      s16x8 vf = *(const s16x8*)(Vrow + c32*32 + g*8);
      a4[u] = mfma16(pa, vf, a4[u]);
    }
  }
  f32x4 accf = a4[0] + a4[1] + a4[2] + a4[3];

  // ---- attnb write: tile-direct, scaled by zinv (no cross-wave combine) ----
  for (int r = 0; r < 4; ++r){
    int row = qi*16 + g*4 + r;
    float zr = zfullinv[row];
    attnb[(size_t)(b*2048 + q0 + row) * 1024 + h*64 + di*16 + (l & 15)] = f2bf(accf[r] * zr);
  }

  // ---- P-store LAST, no trailing barrier: drain overlaps next block past s_endpgm ----
  float* Pb = Pout + ((size_t)(b*16 + h) * 2048 + q0) * 2048;
  for (int jj = 0; jj < 4; ++jj){
    const int kk0 = w * 256 + jj * 64;
    const int cb = kk0 * 2;
    for (int t = 0; t < 8; ++t){
      int row = t * 4 + g;
      unsigned long long pk =
          *(const unsigned long long*)(Ebase + row*4096 + cb + (((l & 15) * 8) ^ ((row & 7) << 4)));
      float zr = zfullinv[row];
      f32x4 ps;
      ps[0] = bf2f((unsigned short)(pk      )) * zr;
      ps[1] = bf2f((unsigned short)(pk >> 16)) * zr;
      ps[2] = bf2f((unsigned short)(pk >> 32)) * zr;
      ps[3] = bf2f((unsigned short)(pk >> 48)) * zr;
      __builtin_nontemporal_store(ps, (f32x4*)&Pb[(size_t)row * 2048 + kk0 + (l & 15) * 4]);
    }
  }
}

extern "C" void kernel_launch(void* const* d_in, const int* in_sizes, int n_in,
                              void* d_out, int out_size, void* d_ws, size_t ws_size,
                              hipStream_t stream)
{
  const float* x  = (const float*)d_in[0];
  const int* mask = (const int*)d_in[1];
  const float* wq = (const float*)d_in[2];
  const float* bq = (const float*)d_in[3];
  const float* wk = (const float*)d_in[4];
  const float* bk = (const float*)d_in[5];
  const float* wv = (const float*)d_in[6];
  const float* bv = (const float*)d_in[7];
  const float* wo = (const float*)d_in[8];
  const float* bo = (const float*)d_in[9];

  char* ws = (char*)d_ws;
  unsigned short* xb    = (unsigned short*)(ws);                 // 8 MB
  unsigned short* wqkvb = (unsigned short*)(ws + 8388608);       // 6 MB
  unsigned short* wob   = (unsigned short*)(ws + 14680064);      // 2 MB
  float*          bqkv  = (float*)(ws + 16777216);               // 12 KB
  unsigned short* qb    = (unsigned short*)(ws + 16793600);      // 8 MB
  unsigned short* kb    = (unsigned short*)(ws + 25182208);      // 8 MB
  unsigned short* vtb   = (unsigned short*)(ws + 33570816);      // 8 MB  [b][d'][s]
  unsigned short* attnb = (unsigned short*)(ws + 41959424);      // 8 MB

  float* fout = (float*)d_out;
  float* Pout = fout + 4194304;

  cvt_kernel<<<8195, 256, 0, stream>>>(x, wq, wk, wv, wo, bq, bk, bv,
                                       (unsigned long long*)xb, (unsigned long long*)wqkvb,
                                       (unsigned long long*)wob, (float4*)bqkv);
  gemm_qkv<<<768, 256, 0, stream>>>(xb, wqkvb, bqkv, qb, kb, vtb);
  attn_kernel<<<2048, 512, 0, stream>>>(qb, kb, vtb, mask, Pout, attnb);
  gemm_out<<<512, 256, 0, stream>>>(attnb, wob, bo, fout);
}

// Round 17
// 271.933 us; speedup vs baseline: 1.5245x; 1.1200x over previous
//
#include <hip/hip_runtime.h>
#include <hip/hip_bf16.h>

#define DEV __device__ __forceinline__

typedef __attribute__((ext_vector_type(8))) __bf16 bf16x8;
typedef __attribute__((ext_vector_type(8))) short s16x8;
typedef __attribute__((ext_vector_type(4))) float f32x4;
typedef __attribute__((ext_vector_type(2))) unsigned long long u64x2;

DEV f32x4 mfma16(s16x8 a, s16x8 b, f32x4 c){
  return __builtin_amdgcn_mfma_f32_16x16x32_bf16(
      __builtin_bit_cast(bf16x8, a), __builtin_bit_cast(bf16x8, b), c, 0, 0, 0);
}

// hardware cvt_pk path (compiler emits v_cvt_pk_bf16_f32)
DEV unsigned int cvtpk(float a, float b){
  float2 t; t.x = a; t.y = b;
  __hip_bfloat162 h = __float22bfloat162_rn(t);
  unsigned int r;
  __builtin_memcpy(&r, &h, 4);
  return r;
}

DEV unsigned short f2bf(float f){
  __hip_bfloat16 h = __float2bfloat16(f);
  unsigned short r;
  __builtin_memcpy(&r, &h, 2);
  return r;
}

DEV float bf2f(unsigned short u){
  return __builtin_bit_cast(float, ((unsigned int)u) << 16);
}

DEV unsigned long long pack4(float4 v){
  return (unsigned long long)cvtpk(v.x, v.y) | ((unsigned long long)cvtpk(v.z, v.w) << 32);
}

DEV unsigned long long pack4f(float a, float b, float c, float d){
  return (unsigned long long)cvtpk(a, b) | ((unsigned long long)cvtpk(c, d) << 32);
}

DEV void async16(const void* g, void* l){
  __builtin_amdgcn_global_load_lds(
      (const __attribute__((address_space(1))) unsigned int*)g,
      (__attribute__((address_space(3))) unsigned int*)l, 16, 0, 0);
}

// ---------------- convert inputs to bf16 ----------------
__global__ __launch_bounds__(256) void cvt_kernel(
    const float* __restrict__ x, const float* __restrict__ wq, const float* __restrict__ wk,
    const float* __restrict__ wv, const float* __restrict__ wo,
    const float* __restrict__ bq, const float* __restrict__ bk, const float* __restrict__ bv,
    unsigned long long* __restrict__ xb, unsigned long long* __restrict__ wqkvb,
    unsigned long long* __restrict__ wob, float4* __restrict__ bqkv)
{
  const int i = blockIdx.x * 256 + threadIdx.x;
  const int X4 = 1048576, W4 = 262144;
  if (i < X4){
    xb[i] = pack4(((const float4*)x)[i]);
  } else if (i < X4 + 3*W4){
    int j = i - X4;
    const float* src = (j < W4) ? wq : (j < 2*W4) ? wk : wv;
    int jj = (j < W4) ? j : (j < 2*W4) ? (j - W4) : (j - 2*W4);
    wqkvb[j] = pack4(((const float4*)src)[jj]);
  } else if (i < X4 + 4*W4){
    int j = i - X4 - 3*W4;
    wob[j] = pack4(((const float4*)wo)[j]);
  } else if (i < X4 + 4*W4 + 768){
    int j = i - X4 - 4*W4;
    const float* src = (j < 256) ? bq : (j < 512) ? bk : bv;
    int jj = (j < 256) ? j : (j < 512) ? (j - 256) : (j - 512);
    bqkv[j] = ((const float4*)src)[jj];
  }
}

// ---------------- 128x128 NT GEMM (QKV fused), K=1024, BK=64, swizzled LDS ----------------
__global__ __launch_bounds__(256) void gemm_qkv(
    const unsigned short* __restrict__ A,
    const unsigned short* __restrict__ B,
    const float* __restrict__ bias,
    unsigned short* __restrict__ oq,
    unsigned short* __restrict__ okk,
    unsigned short* __restrict__ ovt)
{
  __shared__ __align__(16) char smem[32768];
  char* As = smem;
  char* Bs = smem + 16384;
  const int tid = threadIdx.x;
  const int l = tid & 63, w = tid >> 6, g = l >> 4;

  const int orig = blockIdx.x;
  const int lin = (orig & 7) * 96 + (orig >> 3);
  const int m0 = (lin / 24) * 128, n0 = (lin % 24) * 128;
  const int rowbytes = 2048;

  f32x4 acc[4][4] = {};
  const int wr = w >> 1, wc = w & 1;
  const int wm = wr * 64, wn = wc * 64;

  const int srow = w * 32 + (l >> 3);
  const int scol = (((l & 7) ^ (l >> 3)) << 4);
  const char* Abp = (const char*)A + (size_t)(m0 + srow) * rowbytes + scol;
  const char* Bbp = (const char*)B + (size_t)(n0 + srow) * rowbytes + scol;
  char* Asw = As + w * 4096;
  char* Bsw = Bs + w * 4096;

  int aoff[4][2], boff[4][2];
  for (int mf = 0; mf < 4; ++mf)
    for (int ks = 0; ks < 2; ++ks){
      int ra = wm + mf * 16 + (l & 15);
      aoff[mf][ks] = ra * 128 + ((ks * 64 + g * 16) ^ ((l & 7) << 4));
      int rb = wn + mf * 16 + (l & 15);
      boff[mf][ks] = rb * 128 + ((ks * 64 + g * 16) ^ ((l & 7) << 4));
    }

  for (int kt = 0; kt < 16; ++kt){
    const char* ab = Abp + kt * 128;
    const char* bb = Bbp + kt * 128;
    for (int i = 0; i < 4; ++i){
      async16(ab + (size_t)i * 8 * rowbytes, Asw + i * 1024);
      async16(bb + (size_t)i * 8 * rowbytes, Bsw + i * 1024);
    }
    __syncthreads();
    for (int ks = 0; ks < 2; ++ks){
      s16x8 af[4], bf[4];
      for (int mf = 0; mf < 4; ++mf) af[mf] = *(const s16x8*)(As + aoff[mf][ks]);
      for (int nf = 0; nf < 4; ++nf) bf[nf] = *(const s16x8*)(Bs + boff[nf][ks]);
      for (int mf = 0; mf < 4; ++mf)
        for (int nf = 0; nf < 4; ++nf)
          acc[mf][nf] = mfma16(af[mf], bf[nf], acc[mf][nf]);
    }
    __syncthreads();
  }

  if (n0 >= 2048){
    for (int nf = 0; nf < 4; ++nf){
      int nloc = wn + nf * 16 + (l & 15);
      float bs = bias[n0 + nloc];
      for (int mf = 0; mf < 4; ++mf){
        int mby = (wm + mf * 16 + g * 4) * 2;
        unsigned long long pk = pack4f(acc[mf][nf][0] + bs, acc[mf][nf][1] + bs,
                                       acc[mf][nf][2] + bs, acc[mf][nf][3] + bs);
        *(unsigned long long*)(smem + nloc * 256 + (mby ^ ((nloc & 15) << 4))) = pk;
      }
    }
    __syncthreads();
    int b2 = m0 >> 11, s0 = m0 & 2047;
    for (int i = 0; i < 8; ++i){
      int idx = i * 256 + tid;
      int row = idx >> 4, c8 = (idx & 15) * 8;
      s16x8 vv = *(const s16x8*)(smem + row * 256 + ((c8 * 2) ^ ((row & 15) << 4)));
      *(s16x8*)(ovt + (size_t)(b2 * 1024 + (n0 - 2048) + row) * 2048 + s0 + c8) = vv;
    }
    return;
  }

  for (int mf = 0; mf < 4; ++mf)
    for (int nf = 0; nf < 4; ++nf)
      for (int r = 0; r < 4; ++r){
        int grow = m0 + wm + mf * 16 + g * 4 + r;
        int n = n0 + wn + nf * 16 + (l & 15);
        float v = acc[mf][nf][r] + bias[n];
        if (n < 1024) oq [(size_t)grow * 1024 + n]          = f2bf(v);
        else          okk[(size_t)grow * 1024 + (n - 1024)] = f2bf(v);
      }
}

// ---------------- out-proj GEMM: 128x64 tiles, 512 blocks (2/CU), coalesced f32 epilogue ----
__global__ __launch_bounds__(256) void gemm_out(
    const unsigned short* __restrict__ A,
    const unsigned short* __restrict__ B,
    const float* __restrict__ bias,
    float* __restrict__ of)
{
  __shared__ __align__(16) char smem[32768];
  char* As = smem;
  char* Bs = smem + 16384;
  const int tid = threadIdx.x, l = tid & 63, w = tid >> 6, g = l >> 4;
  const int orig = blockIdx.x;
  const int lin = (orig & 7) * 64 + (orig >> 3);
  const int m0 = (lin >> 4) * 128, n0 = (lin & 15) * 64;
  const int rowbytes = 2048;

  f32x4 acc[2][4] = {};
  const int wm = w * 32;

  const int scol = (((l & 7) ^ (l >> 3)) << 4);
  const char* Abp = (const char*)A + (size_t)(m0 + w * 32 + (l >> 3)) * rowbytes + scol;
  const char* Bbp = (const char*)B + (size_t)(n0 + w * 16 + (l >> 3)) * rowbytes + scol;
  char* Asw = As + w * 4096;
  char* Bsw = Bs + w * 2048;

  int aoff[2][2], boff[4][2];
  for (int ks = 0; ks < 2; ++ks){
    for (int mf = 0; mf < 2; ++mf){
      int ra = wm + mf * 16 + (l & 15);
      aoff[mf][ks] = ra * 128 + ((ks * 64 + g * 16) ^ ((l & 7) << 4));
    }
    for (int nf = 0; nf < 4; ++nf){
      int rb = nf * 16 + (l & 15);
      boff[nf][ks] = rb * 128 + ((ks * 64 + g * 16) ^ ((l & 7) << 4));
    }
  }

  for (int kt = 0; kt < 16; ++kt){
    for (int i = 0; i < 4; ++i)
      async16(Abp + kt * 128 + (size_t)i * 8 * rowbytes, Asw + i * 1024);
    for (int i = 0; i < 2; ++i)
      async16(Bbp + kt * 128 + (size_t)i * 8 * rowbytes, Bsw + i * 1024);
    __syncthreads();
    for (int ks = 0; ks < 2; ++ks){
      s16x8 af[2], bf[4];
      for (int mf = 0; mf < 2; ++mf) af[mf] = *(const s16x8*)(As + aoff[mf][ks]);
      for (int nf = 0; nf < 4; ++nf) bf[nf] = *(const s16x8*)(Bs + boff[nf][ks]);
      for (int mf = 0; mf < 2; ++mf)
        for (int nf = 0; nf < 4; ++nf)
          acc[mf][nf] = mfma16(af[mf], bf[nf], acc[mf][nf]);
    }
    __syncthreads();
  }

  __syncthreads();
  char* stg = smem + w * 8192;
  float bv4[4];
  for (int nf = 0; nf < 4; ++nf) bv4[nf] = bias[n0 + nf * 16 + (l & 15)];
  for (int mf = 0; mf < 2; ++mf)
    for (int nf = 0; nf < 4; ++nf)
      for (int r = 0; r < 4; ++r){
        int row = mf * 16 + g * 4 + r;
        int colb = (nf * 16 + (l & 15)) * 4;
        *(float*)(stg + row * 256 + (colb ^ ((row & 7) << 4))) = acc[mf][nf][r] + bv4[nf];
      }
  __syncthreads();
  for (int t = 0; t < 8; ++t){
    int row = t * 4 + (l >> 4);
    int colb = ((l & 15) * 16) ^ ((row & 7) << 4);
    f32x4 v = *(const f32x4*)(stg + row * 256 + colb);
    __builtin_nontemporal_store(v, (f32x4*)&of[(size_t)(m0 + wm + row) * 1024 + n0 + (l & 15) * 4]);
  }
}

// ---------------- attention: SINGLE-PASS, QBLK=32, 8 waves x 256-key stripes (R11 champion).
// R17 A/B: P stores are REGULAR (not non-temporal). Theory: vmcnt is an in-order counter,
// so pass2's V-load waits serialize behind older P-stores; nt stores complete at HBM-accept
// rate (slow under saturation) while regular stores complete at L2-accept (fast) and the L2
// evicts to HBM in the background -> store drain overlaps compute for free.
__global__ __launch_bounds__(512) void attn_kernel(
    const unsigned short* __restrict__ qb,
    const unsigned short* __restrict__ kb,
    const unsigned short* __restrict__ vtb,
    const int* __restrict__ mask,
    float* __restrict__ Pout,
    unsigned short* __restrict__ attnb)
{
  const int flat = blockIdx.x;
  const int sw = (flat & 7) * 256 + (flat >> 3);
  const int qt = sw & 63, h = (sw >> 6) & 15, b = sw >> 10;
  const int tid = threadIdx.x, l = tid & 63, w = tid >> 6, g = l >> 4;
  const int q0 = qt * 32;

  __shared__ __align__(16) unsigned long long estu[16384]; // 128 KB: [32 q][4096 B] E; reused as 8 pv bufs
  __shared__ float maskadd[2048];                          // 8 KB
  __shared__ float zpart[8][32];
  __shared__ float zfullinv[32];

  char* Ebase = (char*)estu;

  for (int i = tid; i < 2048; i += 512)
    maskadd[i] = mask[b * 2048 + i] ? 0.0f : -1e30f;

  s16x8 qf[2][2];
  for (int mf = 0; mf < 2; ++mf)
    for (int ks = 0; ks < 2; ++ks)
      qf[mf][ks] = *(const s16x8*)(qb + (size_t)(b*2048 + q0 + mf*16 + (l&15)) * 1024
                                   + h*64 + ks*32 + g*8);

  const unsigned short* Kb = kb + (size_t)b * 2048 * 1024 + h * 64;
  const unsigned short* Vb = vtb + ((size_t)b * 1024 + h * 64) * 2048;

  __syncthreads();

  // ---- pass 1: QK^T + exp + E->LDS + Z (wave w owns keys [w*256, w*256+256)) ----
  float zacc[2] = {0.0f, 0.0f};
  for (int jj = 0; jj < 4; ++jj){
    const int kk0 = w * 256 + jj * 64;
    const int cb = kk0 * 2;
    f32x4 c[2][4] = {};
    for (int nh = 0; nh < 2; ++nh){
      s16x8 kf[2][2];
      for (int n2 = 0; n2 < 2; ++n2)
        for (int ks = 0; ks < 2; ++ks)
          kf[n2][ks] = *(const s16x8*)(Kb + (size_t)(kk0 + (nh*2+n2)*16 + (l&15)) * 1024 + ks*32 + g*8);
      __builtin_amdgcn_s_setprio(1);
      for (int ks = 0; ks < 2; ++ks)
        for (int mf = 0; mf < 2; ++mf)
          for (int n2 = 0; n2 < 2; ++n2)
            c[mf][nh*2+n2] = mfma16(kf[n2][ks], qf[mf][ks], c[mf][nh*2+n2]);
      __builtin_amdgcn_s_setprio(0);
    }
    for (int mf = 0; mf < 2; ++mf){
      int q = mf*16 + (l & 15);
      for (int nf = 0; nf < 4; ++nf){
        f32x4 ma = *(const f32x4*)&maskadd[kk0 + nf*16 + g*4];
        f32x4 e;
        for (int r = 0; r < 4; ++r){
          e[r] = __expf(fmaf(c[mf][nf][r], 0.125f, ma[r]));
          zacc[mf] += e[r];
        }
        *(unsigned long long*)(Ebase + q*4096 + cb + ((nf*32 + g*8) ^ ((q & 7) << 4))) =
            pack4f(e[0], e[1], e[2], e[3]);
      }
    }
  }
  for (int mf = 0; mf < 2; ++mf){
    float z = zacc[mf];
    z += __shfl_xor(z, 16, 64);
    z += __shfl_xor(z, 32, 64);
    zacc[mf] = z;
  }
  if (g == 0){
    zpart[w][l & 15]        = zacc[0];
    zpart[w][16 + (l & 15)] = zacc[1];
  }
  __syncthreads();
  if (tid < 32){
    float s = 0.0f;
    for (int ww = 0; ww < 8; ++ww) s += zpart[ww][tid];
    zfullinv[tid] = 1.0f / s;
  }
  __syncthreads();

  // ---- pass 2 (E read-only): PV partials + coalesced P store (regular, L2-buffered) ----
  float* Pb = Pout + ((size_t)(b*16 + h) * 2048 + q0) * 2048;
  f32x4 pv[2][4] = {};
  for (int jj = 0; jj < 4; ++jj){
    const int kk0 = w * 256 + jj * 64;
    const int cb = kk0 * 2;
    s16x8 pa[2][2];
    for (int mf = 0; mf < 2; ++mf)
      for (int ks = 0; ks < 2; ++ks){
        int q = mf*16 + (l & 15);
        const unsigned long long* pp =
            (const unsigned long long*)(Ebase + q*4096 + cb + ((ks*64 + g*16) ^ ((q & 7) << 4)));
        u64x2 t; t[0] = pp[0]; t[1] = pp[1];
        pa[mf][ks] = __builtin_bit_cast(s16x8, t);
      }
    for (int dh = 0; dh < 2; ++dh){
      s16x8 vf[2][2];
      for (int d2 = 0; d2 < 2; ++d2)
        for (int ks = 0; ks < 2; ++ks)
          vf[d2][ks] = *(const s16x8*)(Vb + (size_t)((dh*2+d2)*16 + (l&15)) * 2048 + kk0 + ks*32 + g*8);
      __builtin_amdgcn_s_setprio(1);
      for (int ks = 0; ks < 2; ++ks)
        for (int mf = 0; mf < 2; ++mf)
          for (int d2 = 0; d2 < 2; ++d2)
            pv[mf][dh*2+d2] = mfma16(pa[mf][ks], vf[d2][ks], pv[mf][dh*2+d2]);
      __builtin_amdgcn_s_setprio(0);
    }
    for (int t = 0; t < 8; ++t){
      int row = t * 4 + (l >> 4);
      unsigned long long pk =
          *(const unsigned long long*)(Ebase + row*4096 + cb + (((l & 15) * 8) ^ ((row & 7) << 4)));
      float zr = zfullinv[row];
      f32x4 ps;
      ps[0] = bf2f((unsigned short)(pk      )) * zr;
      ps[1] = bf2f((unsigned short)(pk >> 16)) * zr;
      ps[2] = bf2f((unsigned short)(pk >> 32)) * zr;
      ps[3] = bf2f((unsigned short)(pk >> 48)) * zr;
      *(f32x4*)&Pb[(size_t)row * 2048 + kk0 + (l & 15) * 4] = ps;   // regular store (A/B vs nt)
    }
  }

  // ---- combine: 8 partial bufs overlay dead E (barrier-fenced), tree sum, scale, write attnb ----
  __syncthreads();
  char* bufw = Ebase + w * 8192;
  for (int mf = 0; mf < 2; ++mf)
    for (int dn = 0; dn < 4; ++dn)
      for (int r = 0; r < 4; ++r){
        int row = mf*16 + g*4 + r, col = dn*16 + (l & 15);
        *(float*)(bufw + row*256 + ((col*4) ^ (((row >> 2) & 3) << 6))) = pv[mf][dn][r];
      }
  __syncthreads();
  {
    int row = tid >> 4, c4 = (tid & 15) * 4;
    int off = row*256 + ((c4*4) ^ (((row >> 2) & 3) << 6));
    f32x4 s = {};
    for (int ww = 0; ww < 8; ++ww)
      s += *(const f32x4*)(Ebase + ww*8192 + off);
    float zr = zfullinv[row];
    unsigned long long ov = pack4f(s[0]*zr, s[1]*zr, s[2]*zr, s[3]*zr);
    *(unsigned long long*)&attnb[(size_t)(b*2048 + q0 + row) * 1024 + h*64 + c4] = ov;
  }
}

extern "C" void kernel_launch(void* const* d_in, const int* in_sizes, int n_in,
                              void* d_out, int out_size, void* d_ws, size_t ws_size,
                              hipStream_t stream)
{
  const float* x  = (const float*)d_in[0];
  const int* mask = (const int*)d_in[1];
  const float* wq = (const float*)d_in[2];
  const float* bq = (const float*)d_in[3];
  const float* wk = (const float*)d_in[4];
  const float* bk = (const float*)d_in[5];
  const float* wv = (const float*)d_in[6];
  const float* bv = (const float*)d_in[7];
  const float* wo = (const float*)d_in[8];
  const float* bo = (const float*)d_in[9];

  char* ws = (char*)d_ws;
  unsigned short* xb    = (unsigned short*)(ws);                 // 8 MB
  unsigned short* wqkvb = (unsigned short*)(ws + 8388608);       // 6 MB
  unsigned short* wob   = (unsigned short*)(ws + 14680064);      // 2 MB
  float*          bqkv  = (float*)(ws + 16777216);               // 12 KB
  unsigned short* qb    = (unsigned short*)(ws + 16793600);      // 8 MB
  unsigned short* kb    = (unsigned short*)(ws + 25182208);      // 8 MB
  unsigned short* vtb   = (unsigned short*)(ws + 33570816);      // 8 MB  [b][d'][s]
  unsigned short* attnb = (unsigned short*)(ws + 41959424);      // 8 MB

  float* fout = (float*)d_out;
  float* Pout = fout + 4194304;

  cvt_kernel<<<8195, 256, 0, stream>>>(x, wq, wk, wv, wo, bq, bk, bv,
                                       (unsigned long long*)xb, (unsigned long long*)wqkvb,
                                       (unsigned long long*)wob, (float4*)bqkv);
  gemm_qkv<<<768, 256, 0, stream>>>(xb, wqkvb, bqkv, qb, kb, vtb);
  attn_kernel<<<2048, 512, 0, stream>>>(qb, kb, vtb, mask, Pout, attnb);
  gemm_out<<<512, 256, 0, stream>>>(attnb, wob, bo, fout);
}

// Round 18
// 253.270 us; speedup vs baseline: 1.6369x; 1.0737x over previous
//
#include <hip/hip_runtime.h>
#include <hip/hip_bf16.h>

#define DEV __device__ __forceinline__

typedef __attribute__((ext_vector_type(8))) __bf16 bf16x8;
typedef __attribute__((ext_vector_type(8))) short s16x8;
typedef __attribute__((ext_vector_type(4))) float f32x4;
typedef __attribute__((ext_vector_type(2))) unsigned long long u64x2;

DEV f32x4 mfma16(s16x8 a, s16x8 b, f32x4 c){
  return __builtin_amdgcn_mfma_f32_16x16x32_bf16(
      __builtin_bit_cast(bf16x8, a), __builtin_bit_cast(bf16x8, b), c, 0, 0, 0);
}

// hardware cvt_pk path (compiler emits v_cvt_pk_bf16_f32)
DEV unsigned int cvtpk(float a, float b){
  float2 t; t.x = a; t.y = b;
  __hip_bfloat162 h = __float22bfloat162_rn(t);
  unsigned int r;
  __builtin_memcpy(&r, &h, 4);
  return r;
}

DEV unsigned short f2bf(float f){
  __hip_bfloat16 h = __float2bfloat16(f);
  unsigned short r;
  __builtin_memcpy(&r, &h, 2);
  return r;
}

DEV float bf2f(unsigned short u){
  return __builtin_bit_cast(float, ((unsigned int)u) << 16);
}

DEV unsigned long long pack4(float4 v){
  return (unsigned long long)cvtpk(v.x, v.y) | ((unsigned long long)cvtpk(v.z, v.w) << 32);
}

DEV unsigned long long pack4f(float a, float b, float c, float d){
  return (unsigned long long)cvtpk(a, b) | ((unsigned long long)cvtpk(c, d) << 32);
}

DEV void async16(const void* g, void* l){
  __builtin_amdgcn_global_load_lds(
      (const __attribute__((address_space(1))) unsigned int*)g,
      (__attribute__((address_space(3))) unsigned int*)l, 16, 0, 0);
}

// ---------------- convert inputs to bf16 ----------------
__global__ __launch_bounds__(256) void cvt_kernel(
    const float* __restrict__ x, const float* __restrict__ wq, const float* __restrict__ wk,
    const float* __restrict__ wv, const float* __restrict__ wo,
    const float* __restrict__ bq, const float* __restrict__ bk, const float* __restrict__ bv,
    unsigned long long* __restrict__ xb, unsigned long long* __restrict__ wqkvb,
    unsigned long long* __restrict__ wob, float4* __restrict__ bqkv)
{
  const int i = blockIdx.x * 256 + threadIdx.x;
  const int X4 = 1048576, W4 = 262144;
  if (i < X4){
    xb[i] = pack4(((const float4*)x)[i]);
  } else if (i < X4 + 3*W4){
    int j = i - X4;
    const float* src = (j < W4) ? wq : (j < 2*W4) ? wk : wv;
    int jj = (j < W4) ? j : (j < 2*W4) ? (j - W4) : (j - 2*W4);
    wqkvb[j] = pack4(((const float4*)src)[jj]);
  } else if (i < X4 + 4*W4){
    int j = i - X4 - 3*W4;
    wob[j] = pack4(((const float4*)wo)[j]);
  } else if (i < X4 + 4*W4 + 768){
    int j = i - X4 - 4*W4;
    const float* src = (j < 256) ? bq : (j < 512) ? bk : bv;
    int jj = (j < 256) ? j : (j < 512) ? (j - 256) : (j - 512);
    bqkv[j] = ((const float4*)src)[jj];
  }
}

// ---------------- 128x128 NT GEMM (QKV fused), K=1024, BK=64, swizzled LDS ----------------
__global__ __launch_bounds__(256) void gemm_qkv(
    const unsigned short* __restrict__ A,
    const unsigned short* __restrict__ B,
    const float* __restrict__ bias,
    unsigned short* __restrict__ oq,
    unsigned short* __restrict__ okk,
    unsigned short* __restrict__ ovt)
{
  __shared__ __align__(16) char smem[32768];
  char* As = smem;
  char* Bs = smem + 16384;
  const int tid = threadIdx.x;
  const int l = tid & 63, w = tid >> 6, g = l >> 4;

  const int orig = blockIdx.x;
  const int lin = (orig & 7) * 96 + (orig >> 3);
  const int m0 = (lin / 24) * 128, n0 = (lin % 24) * 128;
  const int rowbytes = 2048;

  f32x4 acc[4][4] = {};
  const int wr = w >> 1, wc = w & 1;
  const int wm = wr * 64, wn = wc * 64;

  const int srow = w * 32 + (l >> 3);
  const int scol = (((l & 7) ^ (l >> 3)) << 4);
  const char* Abp = (const char*)A + (size_t)(m0 + srow) * rowbytes + scol;
  const char* Bbp = (const char*)B + (size_t)(n0 + srow) * rowbytes + scol;
  char* Asw = As + w * 4096;
  char* Bsw = Bs + w * 4096;

  int aoff[4][2], boff[4][2];
  for (int mf = 0; mf < 4; ++mf)
    for (int ks = 0; ks < 2; ++ks){
      int ra = wm + mf * 16 + (l & 15);
      aoff[mf][ks] = ra * 128 + ((ks * 64 + g * 16) ^ ((l & 7) << 4));
      int rb = wn + mf * 16 + (l & 15);
      boff[mf][ks] = rb * 128 + ((ks * 64 + g * 16) ^ ((l & 7) << 4));
    }

  for (int kt = 0; kt < 16; ++kt){
    const char* ab = Abp + kt * 128;
    const char* bb = Bbp + kt * 128;
    for (int i = 0; i < 4; ++i){
      async16(ab + (size_t)i * 8 * rowbytes, Asw + i * 1024);
      async16(bb + (size_t)i * 8 * rowbytes, Bsw + i * 1024);
    }
    __syncthreads();
    for (int ks = 0; ks < 2; ++ks){
      s16x8 af[4], bf[4];
      for (int mf = 0; mf < 4; ++mf) af[mf] = *(const s16x8*)(As + aoff[mf][ks]);
      for (int nf = 0; nf < 4; ++nf) bf[nf] = *(const s16x8*)(Bs + boff[nf][ks]);
      for (int mf = 0; mf < 4; ++mf)
        for (int nf = 0; nf < 4; ++nf)
          acc[mf][nf] = mfma16(af[mf], bf[nf], acc[mf][nf]);
    }
    __syncthreads();
  }

  if (n0 >= 2048){
    for (int nf = 0; nf < 4; ++nf){
      int nloc = wn + nf * 16 + (l & 15);
      float bs = bias[n0 + nloc];
      for (int mf = 0; mf < 4; ++mf){
        int mby = (wm + mf * 16 + g * 4) * 2;
        unsigned long long pk = pack4f(acc[mf][nf][0] + bs, acc[mf][nf][1] + bs,
                                       acc[mf][nf][2] + bs, acc[mf][nf][3] + bs);
        *(unsigned long long*)(smem + nloc * 256 + (mby ^ ((nloc & 15) << 4))) = pk;
      }
    }
    __syncthreads();
    int b2 = m0 >> 11, s0 = m0 & 2047;
    for (int i = 0; i < 8; ++i){
      int idx = i * 256 + tid;
      int row = idx >> 4, c8 = (idx & 15) * 8;
      s16x8 vv = *(const s16x8*)(smem + row * 256 + ((c8 * 2) ^ ((row & 15) << 4)));
      *(s16x8*)(ovt + (size_t)(b2 * 1024 + (n0 - 2048) + row) * 2048 + s0 + c8) = vv;
    }
    return;
  }

  for (int mf = 0; mf < 4; ++mf)
    for (int nf = 0; nf < 4; ++nf)
      for (int r = 0; r < 4; ++r){
        int grow = m0 + wm + mf * 16 + g * 4 + r;
        int n = n0 + wn + nf * 16 + (l & 15);
        float v = acc[mf][nf][r] + bias[n];
        if (n < 1024) oq [(size_t)grow * 1024 + n]          = f2bf(v);
        else          okk[(size_t)grow * 1024 + (n - 1024)] = f2bf(v);
      }
}

// ---------------- out-proj GEMM: 128x64 tiles, 512 blocks (2/CU), coalesced f32 epilogue ----
__global__ __launch_bounds__(256) void gemm_out(
    const unsigned short* __restrict__ A,
    const unsigned short* __restrict__ B,
    const float* __restrict__ bias,
    float* __restrict__ of)
{
  __shared__ __align__(16) char smem[32768];
  char* As = smem;
  char* Bs = smem + 16384;
  const int tid = threadIdx.x, l = tid & 63, w = tid >> 6, g = l >> 4;
  const int orig = blockIdx.x;
  const int lin = (orig & 7) * 64 + (orig >> 3);
  const int m0 = (lin >> 4) * 128, n0 = (lin & 15) * 64;
  const int rowbytes = 2048;

  f32x4 acc[2][4] = {};
  const int wm = w * 32;

  const int scol = (((l & 7) ^ (l >> 3)) << 4);
  const char* Abp = (const char*)A + (size_t)(m0 + w * 32 + (l >> 3)) * rowbytes + scol;
  const char* Bbp = (const char*)B + (size_t)(n0 + w * 16 + (l >> 3)) * rowbytes + scol;
  char* Asw = As + w * 4096;
  char* Bsw = Bs + w * 2048;

  int aoff[2][2], boff[4][2];
  for (int ks = 0; ks < 2; ++ks){
    for (int mf = 0; mf < 2; ++mf){
      int ra = wm + mf * 16 + (l & 15);
      aoff[mf][ks] = ra * 128 + ((ks * 64 + g * 16) ^ ((l & 7) << 4));
    }
    for (int nf = 0; nf < 4; ++nf){
      int rb = nf * 16 + (l & 15);
      boff[nf][ks] = rb * 128 + ((ks * 64 + g * 16) ^ ((l & 7) << 4));
    }
  }

  for (int kt = 0; kt < 16; ++kt){
    for (int i = 0; i < 4; ++i)
      async16(Abp + kt * 128 + (size_t)i * 8 * rowbytes, Asw + i * 1024);
    for (int i = 0; i < 2; ++i)
      async16(Bbp + kt * 128 + (size_t)i * 8 * rowbytes, Bsw + i * 1024);
    __syncthreads();
    for (int ks = 0; ks < 2; ++ks){
      s16x8 af[2], bf[4];
      for (int mf = 0; mf < 2; ++mf) af[mf] = *(const s16x8*)(As + aoff[mf][ks]);
      for (int nf = 0; nf < 4; ++nf) bf[nf] = *(const s16x8*)(Bs + boff[nf][ks]);
      for (int mf = 0; mf < 2; ++mf)
        for (int nf = 0; nf < 4; ++nf)
          acc[mf][nf] = mfma16(af[mf], bf[nf], acc[mf][nf]);
    }
    __syncthreads();
  }

  __syncthreads();
  char* stg = smem + w * 8192;
  float bv4[4];
  for (int nf = 0; nf < 4; ++nf) bv4[nf] = bias[n0 + nf * 16 + (l & 15)];
  for (int mf = 0; mf < 2; ++mf)
    for (int nf = 0; nf < 4; ++nf)
      for (int r = 0; r < 4; ++r){
        int row = mf * 16 + g * 4 + r;
        int colb = (nf * 16 + (l & 15)) * 4;
        *(float*)(stg + row * 256 + (colb ^ ((row & 7) << 4))) = acc[mf][nf][r] + bv4[nf];
      }
  __syncthreads();
  for (int t = 0; t < 8; ++t){
    int row = t * 4 + (l >> 4);
    int colb = ((l & 15) * 16) ^ ((row & 7) << 4);
    f32x4 v = *(const f32x4*)(stg + row * 256 + colb);
    __builtin_nontemporal_store(v, (f32x4*)&of[(size_t)(m0 + wm + row) * 1024 + n0 + (l & 15) * 4]);
  }
}

// ---------------- attention: SINGLE-PASS, QBLK=32, 8 waves x 256-key stripes (R11 champion).
// R18: nt P-stores restored (R17 proved L2 pollution > stall cost) + V PREFETCH one jj
// ahead: V loads for jj+1 are ISSUED BEFORE jj's P-stores, so the MFMA's in-order vmcnt
// wait on V retires without draining the nt store queue -> store drain overlaps compute.
__global__ __launch_bounds__(512) void attn_kernel(
    const unsigned short* __restrict__ qb,
    const unsigned short* __restrict__ kb,
    const unsigned short* __restrict__ vtb,
    const int* __restrict__ mask,
    float* __restrict__ Pout,
    unsigned short* __restrict__ attnb)
{
  const int flat = blockIdx.x;
  const int sw = (flat & 7) * 256 + (flat >> 3);
  const int qt = sw & 63, h = (sw >> 6) & 15, b = sw >> 10;
  const int tid = threadIdx.x, l = tid & 63, w = tid >> 6, g = l >> 4;
  const int q0 = qt * 32;

  __shared__ __align__(16) unsigned long long estu[16384]; // 128 KB: [32 q][4096 B] E; reused as 8 pv bufs
  __shared__ float maskadd[2048];                          // 8 KB
  __shared__ float zpart[8][32];
  __shared__ float zfullinv[32];

  char* Ebase = (char*)estu;

  for (int i = tid; i < 2048; i += 512)
    maskadd[i] = mask[b * 2048 + i] ? 0.0f : -1e30f;

  s16x8 qf[2][2];
  for (int mf = 0; mf < 2; ++mf)
    for (int ks = 0; ks < 2; ++ks)
      qf[mf][ks] = *(const s16x8*)(qb + (size_t)(b*2048 + q0 + mf*16 + (l&15)) * 1024
                                   + h*64 + ks*32 + g*8);

  const unsigned short* Kb = kb + (size_t)b * 2048 * 1024 + h * 64;
  const unsigned short* Vb = vtb + ((size_t)b * 1024 + h * 64) * 2048;

  __syncthreads();

  // ---- pass 1: QK^T + exp + E->LDS + Z (wave w owns keys [w*256, w*256+256)) ----
  float zacc[2] = {0.0f, 0.0f};
  for (int jj = 0; jj < 4; ++jj){
    const int kk0 = w * 256 + jj * 64;
    const int cb = kk0 * 2;
    f32x4 c[2][4] = {};
    for (int nh = 0; nh < 2; ++nh){
      s16x8 kf[2][2];
      for (int n2 = 0; n2 < 2; ++n2)
        for (int ks = 0; ks < 2; ++ks)
          kf[n2][ks] = *(const s16x8*)(Kb + (size_t)(kk0 + (nh*2+n2)*16 + (l&15)) * 1024 + ks*32 + g*8);
      __builtin_amdgcn_s_setprio(1);
      for (int ks = 0; ks < 2; ++ks)
        for (int mf = 0; mf < 2; ++mf)
          for (int n2 = 0; n2 < 2; ++n2)
            c[mf][nh*2+n2] = mfma16(kf[n2][ks], qf[mf][ks], c[mf][nh*2+n2]);
      __builtin_amdgcn_s_setprio(0);
    }
    for (int mf = 0; mf < 2; ++mf){
      int q = mf*16 + (l & 15);
      for (int nf = 0; nf < 4; ++nf){
        f32x4 ma = *(const f32x4*)&maskadd[kk0 + nf*16 + g*4];
        f32x4 e;
        for (int r = 0; r < 4; ++r){
          e[r] = __expf(fmaf(c[mf][nf][r], 0.125f, ma[r]));
          zacc[mf] += e[r];
        }
        *(unsigned long long*)(Ebase + q*4096 + cb + ((nf*32 + g*8) ^ ((q & 7) << 4))) =
            pack4f(e[0], e[1], e[2], e[3]);
      }
    }
  }
  for (int mf = 0; mf < 2; ++mf){
    float z = zacc[mf];
    z += __shfl_xor(z, 16, 64);
    z += __shfl_xor(z, 32, 64);
    zacc[mf] = z;
  }
  if (g == 0){
    zpart[w][l & 15]        = zacc[0];
    zpart[w][16 + (l & 15)] = zacc[1];
  }
  __syncthreads();
  if (tid < 32){
    float s = 0.0f;
    for (int ww = 0; ww < 8; ++ww) s += zpart[ww][tid];
    zfullinv[tid] = 1.0f / s;
  }
  __syncthreads();

  // ---- pass 2 (E read-only): V prefetched 1 jj ahead; PV; nt P store last in body ----
  float* Pb = Pout + ((size_t)(b*16 + h) * 2048 + q0) * 2048;
  f32x4 pv[2][4] = {};
  s16x8 vcur[8], vnxt[8];
  {
    const int kk0 = w * 256;
    for (int dn = 0; dn < 4; ++dn)
      for (int ks = 0; ks < 2; ++ks)
        vcur[dn*2+ks] = *(const s16x8*)(Vb + (size_t)(dn*16 + (l&15)) * 2048 + kk0 + ks*32 + g*8);
  }
#pragma unroll
  for (int jj = 0; jj < 4; ++jj){
    const int kk0 = w * 256 + jj * 64;
    const int cb = kk0 * 2;
    s16x8 pa[2][2];
    for (int mf = 0; mf < 2; ++mf)
      for (int ks = 0; ks < 2; ++ks){
        int q = mf*16 + (l & 15);
        const unsigned long long* pp =
            (const unsigned long long*)(Ebase + q*4096 + cb + ((ks*64 + g*16) ^ ((q & 7) << 4)));
        u64x2 t2; t2[0] = pp[0]; t2[1] = pp[1];
        pa[mf][ks] = __builtin_bit_cast(s16x8, t2);
      }
    // prefetch next jj's V BEFORE this jj's stores -> its vmcnt wait skips the store queue
    if (jj < 3){
      const int kn = kk0 + 64;
      for (int dn = 0; dn < 4; ++dn)
        for (int ks = 0; ks < 2; ++ks)
          vnxt[dn*2+ks] = *(const s16x8*)(Vb + (size_t)(dn*16 + (l&15)) * 2048 + kn + ks*32 + g*8);
    }
    __builtin_amdgcn_s_setprio(1);
    for (int ks = 0; ks < 2; ++ks)
      for (int mf = 0; mf < 2; ++mf)
        for (int dn = 0; dn < 4; ++dn)
          pv[mf][dn] = mfma16(pa[mf][ks], vcur[dn*2+ks], pv[mf][dn]);
    __builtin_amdgcn_s_setprio(0);
    for (int t = 0; t < 8; ++t){
      int row = t * 4 + (l >> 4);
      unsigned long long pk =
          *(const unsigned long long*)(Ebase + row*4096 + cb + (((l & 15) * 8) ^ ((row & 7) << 4)));
      float zr = zfullinv[row];
      f32x4 ps;
      ps[0] = bf2f((unsigned short)(pk      )) * zr;
      ps[1] = bf2f((unsigned short)(pk >> 16)) * zr;
      ps[2] = bf2f((unsigned short)(pk >> 32)) * zr;
      ps[3] = bf2f((unsigned short)(pk >> 48)) * zr;
      __builtin_nontemporal_store(ps, (f32x4*)&Pb[(size_t)row * 2048 + kk0 + (l & 15) * 4]);
    }
    if (jj < 3)
      for (int u = 0; u < 8; ++u) vcur[u] = vnxt[u];
  }

  // ---- combine: 8 partial bufs overlay dead E (barrier-fenced), tree sum, scale, write attnb ----
  __syncthreads();
  char* bufw = Ebase + w * 8192;
  for (int mf = 0; mf < 2; ++mf)
    for (int dn = 0; dn < 4; ++dn)
      for (int r = 0; r < 4; ++r){
        int row = mf*16 + g*4 + r, col = dn*16 + (l & 15);
        *(float*)(bufw + row*256 + ((col*4) ^ (((row >> 2) & 3) << 6))) = pv[mf][dn][r];
      }
  __syncthreads();
  {
    int row = tid >> 4, c4 = (tid & 15) * 4;
    int off = row*256 + ((c4*4) ^ (((row >> 2) & 3) << 6));
    f32x4 s = {};
    for (int ww = 0; ww < 8; ++ww)
      s += *(const f32x4*)(Ebase + ww*8192 + off);
    float zr = zfullinv[row];
    unsigned long long ov = pack4f(s[0]*zr, s[1]*zr, s[2]*zr, s[3]*zr);
    *(unsigned long long*)&attnb[(size_t)(b*2048 + q0 + row) * 1024 + h*64 + c4] = ov;
  }
}

extern "C" void kernel_launch(void* const* d_in, const int* in_sizes, int n_in,
                              void* d_out, int out_size, void* d_ws, size_t ws_size,
                              hipStream_t stream)
{
  const float* x  = (const float*)d_in[0];
  const int* mask = (const int*)d_in[1];
  const float* wq = (const float*)d_in[2];
  const float* bq = (const float*)d_in[3];
  const float* wk = (const float*)d_in[4];
  const float* bk = (const float*)d_in[5];
  const float* wv = (const float*)d_in[6];
  const float* bv = (const float*)d_in[7];
  const float* wo = (const float*)d_in[8];
  const float* bo = (const float*)d_in[9];

  char* ws = (char*)d_ws;
  unsigned short* xb    = (unsigned short*)(ws);                 // 8 MB
  unsigned short* wqkvb = (unsigned short*)(ws + 8388608);       // 6 MB
  unsigned short* wob   = (unsigned short*)(ws + 14680064);      // 2 MB
  float*          bqkv  = (float*)(ws + 16777216);               // 12 KB
  unsigned short* qb    = (unsigned short*)(ws + 16793600);      // 8 MB
  unsigned short* kb    = (unsigned short*)(ws + 25182208);      // 8 MB
  unsigned short* vtb   = (unsigned short*)(ws + 33570816);      // 8 MB  [b][d'][s]
  unsigned short* attnb = (unsigned short*)(ws + 41959424);      // 8 MB

  float* fout = (float*)d_out;
  float* Pout = fout + 4194304;

  cvt_kernel<<<8195, 256, 0, stream>>>(x, wq, wk, wv, wo, bq, bk, bv,
                                       (unsigned long long*)xb, (unsigned long long*)wqkvb,
                                       (unsigned long long*)wob, (float4*)bqkv);
  gemm_qkv<<<768, 256, 0, stream>>>(xb, wqkvb, bqkv, qb, kb, vtb);
  attn_kernel<<<2048, 512, 0, stream>>>(qb, kb, vtb, mask, Pout, attnb);
  gemm_out<<<512, 256, 0, stream>>>(attnb, wob, bo, fout);
}

// Round 19
// 229.358 us; speedup vs baseline: 1.8075x; 1.1043x over previous
//
#include <hip/hip_runtime.h>
#include <hip/hip_bf16.h>

#define DEV __device__ __forceinline__

typedef __attribute__((ext_vector_type(8))) __bf16 bf16x8;
typedef __attribute__((ext_vector_type(8))) short s16x8;
typedef __attribute__((ext_vector_type(4))) float f32x4;
typedef __attribute__((ext_vector_type(2))) unsigned long long u64x2;

DEV f32x4 mfma16(s16x8 a, s16x8 b, f32x4 c){
  return __builtin_amdgcn_mfma_f32_16x16x32_bf16(
      __builtin_bit_cast(bf16x8, a), __builtin_bit_cast(bf16x8, b), c, 0, 0, 0);
}

DEV unsigned int cvtpk(float a, float b){
  float2 t; t.x = a; t.y = b;
  __hip_bfloat162 h = __float22bfloat162_rn(t);
  unsigned int r;
  __builtin_memcpy(&r, &h, 4);
  return r;
}

DEV unsigned short f2bf(float f){
  __hip_bfloat16 h = __float2bfloat16(f);
  unsigned short r;
  __builtin_memcpy(&r, &h, 2);
  return r;
}

DEV float bf2f(unsigned short u){
  return __builtin_bit_cast(float, ((unsigned int)u) << 16);
}

DEV unsigned long long pack4(float4 v){
  return (unsigned long long)cvtpk(v.x, v.y) | ((unsigned long long)cvtpk(v.z, v.w) << 32);
}

DEV unsigned long long pack4f(float a, float b, float c, float d){
  return (unsigned long long)cvtpk(a, b) | ((unsigned long long)cvtpk(c, d) << 32);
}

DEV void async16(const void* g, void* l){
  __builtin_amdgcn_global_load_lds(
      (const __attribute__((address_space(1))) unsigned int*)g,
      (__attribute__((address_space(3))) unsigned int*)l, 16, 0, 0);
}

// ---------------- convert inputs to bf16 ----------------
__global__ __launch_bounds__(256) void cvt_kernel(
    const float* __restrict__ x, const float* __restrict__ wq, const float* __restrict__ wk,
    const float* __restrict__ wv, const float* __restrict__ wo,
    const float* __restrict__ bq, const float* __restrict__ bk, const float* __restrict__ bv,
    unsigned long long* __restrict__ xb, unsigned long long* __restrict__ wqkvb,
    unsigned long long* __restrict__ wob, float4* __restrict__ bqkv)
{
  const int i = blockIdx.x * 256 + threadIdx.x;
  const int X4 = 1048576, W4 = 262144;
  if (i < X4){
    xb[i] = pack4(((const float4*)x)[i]);
  } else if (i < X4 + 3*W4){
    int j = i - X4;
    const float* src = (j < W4) ? wq : (j < 2*W4) ? wk : wv;
    int jj = (j < W4) ? j : (j < 2*W4) ? (j - W4) : (j - 2*W4);
    wqkvb[j] = pack4(((const float4*)src)[jj]);
  } else if (i < X4 + 4*W4){
    int j = i - X4 - 3*W4;
    wob[j] = pack4(((const float4*)wo)[j]);
  } else if (i < X4 + 4*W4 + 768){
    int j = i - X4 - 4*W4;
    const float* src = (j < 256) ? bq : (j < 512) ? bk : bv;
    int jj = (j < 256) ? j : (j < 512) ? (j - 256) : (j - 512);
    bqkv[j] = ((const float4*)src)[jj];
  }
}

// ---------------- QKV GEMM: BM=256 x BN=128, 8 waves (512 thr), K=1024, BK=64 ----------------
// 32 MFMA vs 6 staging-calls per thread per K-step (was 16:8 at 128x128) -> 2.7x better
// arithmetic intensity. LDS 48 KB; launch_bounds(512,2) targets <=128 VGPR, 2 blocks/CU.
__global__ __launch_bounds__(512, 2) void gemm_qkv(
    const unsigned short* __restrict__ A,
    const unsigned short* __restrict__ B,
    const float* __restrict__ bias,
    unsigned short* __restrict__ oq,
    unsigned short* __restrict__ okk,
    unsigned short* __restrict__ ovt)
{
  __shared__ __align__(16) char smem[49152];
  char* As = smem;            // 32 KB: 256 rows x 128 B
  char* Bs = smem + 32768;    // 16 KB: 128 rows x 128 B
  const int tid = threadIdx.x;
  const int l = tid & 63, w = tid >> 6, g = l >> 4;

  // XCD-chunked bijective swizzle (grid 384 % 8 == 0)
  const int orig = blockIdx.x;
  const int lin = (orig & 7) * 48 + (orig >> 3);
  const int m0 = (lin / 24) * 256, n0 = (lin % 24) * 128;
  const int rowbytes = 2048;

  f32x4 acc[4][4] = {};
  const int wr = w >> 1, wc = w & 1;        // wave tile: rows wr*64, cols wc*64
  const int wm = wr * 64, wn = wc * 64;

  // staging: linear LDS dest (wave-uniform base + lane*16), inverse-swizzled global source
  const int srow = w * 8 + (l >> 3);        // rows covered per call-round: 64 (8 waves x 8)
  const int scol = (((l & 7) ^ (l >> 3)) << 4);
  const char* Abp = (const char*)A + (size_t)(m0 + srow) * rowbytes + scol;
  const char* Bbp = (const char*)B + (size_t)(n0 + srow) * rowbytes + scol;

  int aoff[4][2], boff[4][2];
  for (int f = 0; f < 4; ++f)
    for (int ks = 0; ks < 2; ++ks){
      int ra = wm + f * 16 + (l & 15);
      aoff[f][ks] = ra * 128 + ((ks * 64 + g * 16) ^ ((l & 7) << 4));
      int rb = wn + f * 16 + (l & 15);
      boff[f][ks] = rb * 128 + ((ks * 64 + g * 16) ^ ((l & 7) << 4));
    }

  for (int kt = 0; kt < 16; ++kt){
    const char* ab = Abp + kt * 128;
    const char* bb = Bbp + kt * 128;
    for (int r = 0; r < 4; ++r)   // A: 4 rounds x 64 rows
      async16(ab + (size_t)r * 64 * rowbytes, As + r * 8192 + w * 1024);
    for (int r = 0; r < 2; ++r)   // B: 2 rounds x 64 rows
      async16(bb + (size_t)r * 64 * rowbytes, Bs + r * 8192 + w * 1024);
    __syncthreads();
    for (int ks = 0; ks < 2; ++ks){
      s16x8 af[4], bf[4];
      for (int mf = 0; mf < 4; ++mf) af[mf] = *(const s16x8*)(As + aoff[mf][ks]);
      for (int nf = 0; nf < 4; ++nf) bf[nf] = *(const s16x8*)(Bs + boff[nf][ks]);
      for (int mf = 0; mf < 4; ++mf)
        for (int nf = 0; nf < 4; ++nf)
          acc[mf][nf] = mfma16(af[mf], bf[nf], acc[mf][nf]);
    }
    __syncthreads();
  }

  if (n0 >= 2048){
    // V section: transpose 256(s) x 128(d) tile via LDS in two 128-s halves (32 KB each)
    const int b2 = m0 >> 11, s0 = m0 & 2047;
    for (int h2 = 0; h2 < 2; ++h2){
      if (wr >> 1 == h2){
        for (int nf = 0; nf < 4; ++nf){
          int nloc = wn + nf * 16 + (l & 15);
          float bs = bias[n0 + nloc];
          for (int mf = 0; mf < 4; ++mf){
            int mby = ((wr & 1) * 64 + mf * 16 + g * 4) * 2;
            unsigned long long pk = pack4f(acc[mf][nf][0] + bs, acc[mf][nf][1] + bs,
                                           acc[mf][nf][2] + bs, acc[mf][nf][3] + bs);
            *(unsigned long long*)(As + nloc * 256 + (mby ^ ((nloc & 15) << 4))) = pk;
          }
        }
      }
      __syncthreads();
      for (int it = 0; it < 4; ++it){
        int idx = it * 512 + tid;
        int drow = idx >> 4, c8 = (idx & 15) * 8;
        s16x8 vv = *(const s16x8*)(As + drow * 256 + ((c8 * 2) ^ ((drow & 15) << 4)));
        *(s16x8*)(ovt + (size_t)(b2 * 1024 + (n0 - 2048) + drow) * 2048 + s0 + h2 * 128 + c8) = vv;
      }
      __syncthreads();
    }
    return;
  }

  for (int mf = 0; mf < 4; ++mf)
    for (int nf = 0; nf < 4; ++nf)
      for (int r = 0; r < 4; ++r){
        int grow = m0 + wm + mf * 16 + g * 4 + r;
        int n = n0 + wn + nf * 16 + (l & 15);
        float v = acc[mf][nf][r] + bias[n];
        if (n < 1024) oq [(size_t)grow * 1024 + n]          = f2bf(v);
        else          okk[(size_t)grow * 1024 + (n - 1024)] = f2bf(v);
      }
}

// ---------------- out-proj GEMM: 128x64 tiles, 512 blocks (2/CU), coalesced f32 epilogue ----
__global__ __launch_bounds__(256) void gemm_out(
    const unsigned short* __restrict__ A,
    const unsigned short* __restrict__ B,
    const float* __restrict__ bias,
    float* __restrict__ of)
{
  __shared__ __align__(16) char smem[32768];
  char* As = smem;
  char* Bs = smem + 16384;
  const int tid = threadIdx.x, l = tid & 63, w = tid >> 6, g = l >> 4;
  const int orig = blockIdx.x;
  const int lin = (orig & 7) * 64 + (orig >> 3);
  const int m0 = (lin >> 4) * 128, n0 = (lin & 15) * 64;
  const int rowbytes = 2048;

  f32x4 acc[2][4] = {};
  const int wm = w * 32;

  const int scol = (((l & 7) ^ (l >> 3)) << 4);
  const char* Abp = (const char*)A + (size_t)(m0 + w * 32 + (l >> 3)) * rowbytes + scol;
  const char* Bbp = (const char*)B + (size_t)(n0 + w * 16 + (l >> 3)) * rowbytes + scol;
  char* Asw = As + w * 4096;
  char* Bsw = Bs + w * 2048;

  int aoff[2][2], boff[4][2];
  for (int ks = 0; ks < 2; ++ks){
    for (int mf = 0; mf < 2; ++mf){
      int ra = wm + mf * 16 + (l & 15);
      aoff[mf][ks] = ra * 128 + ((ks * 64 + g * 16) ^ ((l & 7) << 4));
    }
    for (int nf = 0; nf < 4; ++nf){
      int rb = nf * 16 + (l & 15);
      boff[nf][ks] = rb * 128 + ((ks * 64 + g * 16) ^ ((l & 7) << 4));
    }
  }

  for (int kt = 0; kt < 16; ++kt){
    for (int i = 0; i < 4; ++i)
      async16(Abp + kt * 128 + (size_t)i * 8 * rowbytes, Asw + i * 1024);
    for (int i = 0; i < 2; ++i)
      async16(Bbp + kt * 128 + (size_t)i * 8 * rowbytes, Bsw + i * 1024);
    __syncthreads();
    for (int ks = 0; ks < 2; ++ks){
      s16x8 af[2], bf[4];
      for (int mf = 0; mf < 2; ++mf) af[mf] = *(const s16x8*)(As + aoff[mf][ks]);
      for (int nf = 0; nf < 4; ++nf) bf[nf] = *(const s16x8*)(Bs + boff[nf][ks]);
      for (int mf = 0; mf < 2; ++mf)
        for (int nf = 0; nf < 4; ++nf)
          acc[mf][nf] = mfma16(af[mf], bf[nf], acc[mf][nf]);
    }
    __syncthreads();
  }

  __syncthreads();
  char* stg = smem + w * 8192;
  float bv4[4];
  for (int nf = 0; nf < 4; ++nf) bv4[nf] = bias[n0 + nf * 16 + (l & 15)];
  for (int mf = 0; mf < 2; ++mf)
    for (int nf = 0; nf < 4; ++nf)
      for (int r = 0; r < 4; ++r){
        int row = mf * 16 + g * 4 + r;
        int colb = (nf * 16 + (l & 15)) * 4;
        *(float*)(stg + row * 256 + (colb ^ ((row & 7) << 4))) = acc[mf][nf][r] + bv4[nf];
      }
  __syncthreads();
  for (int t = 0; t < 8; ++t){
    int row = t * 4 + (l >> 4);
    int colb = ((l & 15) * 16) ^ ((row & 7) << 4);
    f32x4 v = *(const f32x4*)(stg + row * 256 + colb);
    __builtin_nontemporal_store(v, (f32x4*)&of[(size_t)(m0 + wm + row) * 1024 + n0 + (l & 15) * 4]);
  }
}

// ---------------- attention: SINGLE-PASS, QBLK=32, 8 waves x 256-key stripes (R11 champion, exact) ----
__global__ __launch_bounds__(512) void attn_kernel(
    const unsigned short* __restrict__ qb,
    const unsigned short* __restrict__ kb,
    const unsigned short* __restrict__ vtb,
    const int* __restrict__ mask,
    float* __restrict__ Pout,
    unsigned short* __restrict__ attnb)
{
  const int flat = blockIdx.x;
  const int sw = (flat & 7) * 256 + (flat >> 3);
  const int qt = sw & 63, h = (sw >> 6) & 15, b = sw >> 10;
  const int tid = threadIdx.x, l = tid & 63, w = tid >> 6, g = l >> 4;
  const int q0 = qt * 32;

  __shared__ __align__(16) unsigned long long estu[16384]; // 128 KB: [32 q][4096 B] E; reused as 8 pv bufs
  __shared__ float maskadd[2048];                          // 8 KB
  __shared__ float zpart[8][32];
  __shared__ float zfullinv[32];

  char* Ebase = (char*)estu;

  for (int i = tid; i < 2048; i += 512)
    maskadd[i] = mask[b * 2048 + i] ? 0.0f : -1e30f;

  s16x8 qf[2][2];
  for (int mf = 0; mf < 2; ++mf)
    for (int ks = 0; ks < 2; ++ks)
      qf[mf][ks] = *(const s16x8*)(qb + (size_t)(b*2048 + q0 + mf*16 + (l&15)) * 1024
                                   + h*64 + ks*32 + g*8);

  const unsigned short* Kb = kb + (size_t)b * 2048 * 1024 + h * 64;
  const unsigned short* Vb = vtb + ((size_t)b * 1024 + h * 64) * 2048;

  __syncthreads();

  // ---- pass 1: QK^T + exp + E->LDS + Z (wave w owns keys [w*256, w*256+256)) ----
  float zacc[2] = {0.0f, 0.0f};
  for (int jj = 0; jj < 4; ++jj){
    const int kk0 = w * 256 + jj * 64;
    const int cb = kk0 * 2;
    f32x4 c[2][4] = {};
    for (int nh = 0; nh < 2; ++nh){
      s16x8 kf[2][2];
      for (int n2 = 0; n2 < 2; ++n2)
        for (int ks = 0; ks < 2; ++ks)
          kf[n2][ks] = *(const s16x8*)(Kb + (size_t)(kk0 + (nh*2+n2)*16 + (l&15)) * 1024 + ks*32 + g*8);
      __builtin_amdgcn_s_setprio(1);
      for (int ks = 0; ks < 2; ++ks)
        for (int mf = 0; mf < 2; ++mf)
          for (int n2 = 0; n2 < 2; ++n2)
            c[mf][nh*2+n2] = mfma16(kf[n2][ks], qf[mf][ks], c[mf][nh*2+n2]);
      __builtin_amdgcn_s_setprio(0);
    }
    for (int mf = 0; mf < 2; ++mf){
      int q = mf*16 + (l & 15);
      for (int nf = 0; nf < 4; ++nf){
        f32x4 ma = *(const f32x4*)&maskadd[kk0 + nf*16 + g*4];
        f32x4 e;
        for (int r = 0; r < 4; ++r){
          e[r] = __expf(fmaf(c[mf][nf][r], 0.125f, ma[r]));
          zacc[mf] += e[r];
        }
        *(unsigned long long*)(Ebase + q*4096 + cb + ((nf*32 + g*8) ^ ((q & 7) << 4))) =
            pack4f(e[0], e[1], e[2], e[3]);
      }
    }
  }
  for (int mf = 0; mf < 2; ++mf){
    float z = zacc[mf];
    z += __shfl_xor(z, 16, 64);
    z += __shfl_xor(z, 32, 64);
    zacc[mf] = z;
  }
  if (g == 0){
    zpart[w][l & 15]        = zacc[0];
    zpart[w][16 + (l & 15)] = zacc[1];
  }
  __syncthreads();
  if (tid < 32){
    float s = 0.0f;
    for (int ww = 0; ww < 8; ++ww) s += zpart[ww][tid];
    zfullinv[tid] = 1.0f / s;
  }
  __syncthreads();

  // ---- pass 2 (E read-only): PV partials + coalesced nt P store ----
  float* Pb = Pout + ((size_t)(b*16 + h) * 2048 + q0) * 2048;
  f32x4 pv[2][4] = {};
  for (int jj = 0; jj < 4; ++jj){
    const int kk0 = w * 256 + jj * 64;
    const int cb = kk0 * 2;
    s16x8 pa[2][2];
    for (int mf = 0; mf < 2; ++mf)
      for (int ks = 0; ks < 2; ++ks){
        int q = mf*16 + (l & 15);
        const unsigned long long* pp =
            (const unsigned long long*)(Ebase + q*4096 + cb + ((ks*64 + g*16) ^ ((q & 7) << 4)));
        u64x2 t; t[0] = pp[0]; t[1] = pp[1];
        pa[mf][ks] = __builtin_bit_cast(s16x8, t);
      }
    for (int dh = 0; dh < 2; ++dh){
      s16x8 vf[2][2];
      for (int d2 = 0; d2 < 2; ++d2)
        for (int ks = 0; ks < 2; ++ks)
          vf[d2][ks] = *(const s16x8*)(Vb + (size_t)((dh*2+d2)*16 + (l&15)) * 2048 + kk0 + ks*32 + g*8);
      __builtin_amdgcn_s_setprio(1);
      for (int ks = 0; ks < 2; ++ks)
        for (int mf = 0; mf < 2; ++mf)
          for (int d2 = 0; d2 < 2; ++d2)
            pv[mf][dh*2+d2] = mfma16(pa[mf][ks], vf[d2][ks], pv[mf][dh*2+d2]);
      __builtin_amdgcn_s_setprio(0);
    }
    for (int t = 0; t < 8; ++t){
      int row = t * 4 + (l >> 4);
      unsigned long long pk =
          *(const unsigned long long*)(Ebase + row*4096 + cb + (((l & 15) * 8) ^ ((row & 7) << 4)));
      float zr = zfullinv[row];
      f32x4 ps;
      ps[0] = bf2f((unsigned short)(pk      )) * zr;
      ps[1] = bf2f((unsigned short)(pk >> 16)) * zr;
      ps[2] = bf2f((unsigned short)(pk >> 32)) * zr;
      ps[3] = bf2f((unsigned short)(pk >> 48)) * zr;
      __builtin_nontemporal_store(ps, (f32x4*)&Pb[(size_t)row * 2048 + kk0 + (l & 15) * 4]);
    }
  }

  // ---- combine: 8 partial bufs overlay dead E (barrier-fenced), tree sum, scale, write attnb ----
  __syncthreads();
  char* bufw = Ebase + w * 8192;
  for (int mf = 0; mf < 2; ++mf)
    for (int dn = 0; dn < 4; ++dn)
      for (int r = 0; r < 4; ++r){
        int row = mf*16 + g*4 + r, col = dn*16 + (l & 15);
        *(float*)(bufw + row*256 + ((col*4) ^ (((row >> 2) & 3) << 6))) = pv[mf][dn][r];
      }
  __syncthreads();
  {
    int row = tid >> 4, c4 = (tid & 15) * 4;
    int off = row*256 + ((c4*4) ^ (((row >> 2) & 3) << 6));
    f32x4 s = {};
    for (int ww = 0; ww < 8; ++ww)
      s += *(const f32x4*)(Ebase + ww*8192 + off);
    float zr = zfullinv[row];
    unsigned long long ov = pack4f(s[0]*zr, s[1]*zr, s[2]*zr, s[3]*zr);
    *(unsigned long long*)&attnb[(size_t)(b*2048 + q0 + row) * 1024 + h*64 + c4] = ov;
  }
}

extern "C" void kernel_launch(void* const* d_in, const int* in_sizes, int n_in,
                              void* d_out, int out_size, void* d_ws, size_t ws_size,
                              hipStream_t stream)
{
  const float* x  = (const float*)d_in[0];
  const int* mask = (const int*)d_in[1];
  const float* wq = (const float*)d_in[2];
  const float* bq = (const float*)d_in[3];
  const float* wk = (const float*)d_in[4];
  const float* bk = (const float*)d_in[5];
  const float* wv = (const float*)d_in[6];
  const float* bv = (const float*)d_in[7];
  const float* wo = (const float*)d_in[8];
  const float* bo = (const float*)d_in[9];

  char* ws = (char*)d_ws;
  unsigned short* xb    = (unsigned short*)(ws);                 // 8 MB
  unsigned short* wqkvb = (unsigned short*)(ws + 8388608);       // 6 MB
  unsigned short* wob   = (unsigned short*)(ws + 14680064);      // 2 MB
  float*          bqkv  = (float*)(ws + 16777216);               // 12 KB
  unsigned short* qb    = (unsigned short*)(ws + 16793600);      // 8 MB
  unsigned short* kb    = (unsigned short*)(ws + 25182208);      // 8 MB
  unsigned short* vtb   = (unsigned short*)(ws + 33570816);      // 8 MB  [b][d'][s]
  unsigned short* attnb = (unsigned short*)(ws + 41959424);      // 8 MB

  float* fout = (float*)d_out;
  float* Pout = fout + 4194304;

  cvt_kernel<<<8195, 256, 0, stream>>>(x, wq, wk, wv, wo, bq, bk, bv,
                                       (unsigned long long*)xb, (unsigned long long*)wqkvb,
                                       (unsigned long long*)wob, (float4*)bqkv);
  gemm_qkv<<<384, 512, 0, stream>>>(xb, wqkvb, bqkv, qb, kb, vtb);
  attn_kernel<<<2048, 512, 0, stream>>>(qb, kb, vtb, mask, Pout, attnb);
  gemm_out<<<512, 256, 0, stream>>>(attnb, wob, bo, fout);
}